// Round 5
// baseline (2628.611 us; speedup 1.0000x reference)
//
#include <hip/hip_runtime.h>
#include <cstdint>

// ============================================================================
// TripleAdaptiveQuantizerV9 — round 10: 4-wave-split scalar-weight MLP k2.
//
// R9 post-mortem: 1-wave-per-m k2 = 597us. 16KB LDS per 64-thr block ->
// 10 waves/CU (2.5/SIMD); VALUBusy 70.8% is the per-CU OR metric — per-SIMD
// issue was only ~30% (1-(1-.3)^4 = .76 matches). Latency-bound, not
// work-bound. R10: split each m across 4 waves (16 output rows each) in a
// 256-thr block. Activations in ONE in-place 16KB column-major XOR-swizzled
// b128-chunked LDS buffer: lane k streams its column via 16 ds_read_b128
// (chunk slot (c&7)^(k&7) = permutation per 8-lane group -> conflict-free),
// acc[16] in regs, barrier, 4 ds_write_b128 back in place. VGPR ~100 ->
// 16 waves/CU (2.2x R9) with 1/4 the per-wave work. Weights stay on the
// scalar pipe (wave-uniform). Features + phase C verbatim on wave 0; heads
// split 5 rows/wave (R5 pattern). All chains bias + ascending-i fmaf; all
// values pass through f32 LDS exactly -> ly/lh/ld bit-identical ->
// flags / kfix / outputs unchanged. Only k2 changed vs R9.
// ============================================================================

#define JAX_PARTITIONABLE 1

constexpr int BL = 64 * 256;  // 16384 (B*L)

// Output offsets (floats)
constexpr long long O_vq  = 0;
constexpr long long O_Hq  = 2097152;
constexpr long long O_yq  = 18874368;
constexpr long long O_eb  = 19136512;
constexpr long long O_wy  = 20185088;
constexpr long long O_wH  = 20283392;
constexpr long long O_wd  = 26574848;
constexpr long long O_yba = 32866304;
constexpr long long O_Hbl = 32882688;
constexpr long long O_dbl = 33931264;

// flag stash inside the v_q region (k4 overwrites all of v_q afterwards)
constexpr long long F_SAMPLE = 0;        // 1048576 bytes, 1 per (m,k)
constexpr long long F_M      = 1048576;  // 16384 bytes, 1 per m

#define MARGIN_THETA 3e-4

// Column-major swizzled activation layout: column k occupies floats
// [k*64, k*64+64); 16B chunk c of column k lives at chunk slot c^(k&15).
// float index:
#define HOFF(k, c) (((k) << 6) + ((((c) ^ ((k) & 15))) << 2))

// ---------------------------------------------------------------- threefry
__device__ __forceinline__ uint32_t rotl32(uint32_t v, int d) {
  return (v << d) | (v >> (32 - d));
}

__device__ __forceinline__ void threefry2x32(uint32_t k0, uint32_t k1,
                                             uint32_t x0, uint32_t x1,
                                             uint32_t& o0, uint32_t& o1) {
  const uint32_t ks2 = k0 ^ k1 ^ 0x1BD11BDAu;
  x0 += k0; x1 += k1;
  x0 += x1; x1 = rotl32(x1, 13); x1 ^= x0;
  x0 += x1; x1 = rotl32(x1, 15); x1 ^= x0;
  x0 += x1; x1 = rotl32(x1, 26); x1 ^= x0;
  x0 += x1; x1 = rotl32(x1, 6);  x1 ^= x0;
  x0 += k1; x1 += ks2 + 1u;
  x0 += x1; x1 = rotl32(x1, 17); x1 ^= x0;
  x0 += x1; x1 = rotl32(x1, 29); x1 ^= x0;
  x0 += x1; x1 = rotl32(x1, 16); x1 ^= x0;
  x0 += x1; x1 = rotl32(x1, 24); x1 ^= x0;
  x0 += ks2; x1 += k0 + 2u;
  x0 += x1; x1 = rotl32(x1, 13); x1 ^= x0;
  x0 += x1; x1 = rotl32(x1, 15); x1 ^= x0;
  x0 += x1; x1 = rotl32(x1, 26); x1 ^= x0;
  x0 += x1; x1 = rotl32(x1, 6);  x1 ^= x0;
  x0 += k0; x1 += k1 + 3u;
  x0 += x1; x1 = rotl32(x1, 17); x1 ^= x0;
  x0 += x1; x1 = rotl32(x1, 29); x1 ^= x0;
  x0 += x1; x1 = rotl32(x1, 16); x1 ^= x0;
  x0 += x1; x1 = rotl32(x1, 24); x1 ^= x0;
  x0 += k1; x1 += ks2 + 4u;
  x0 += x1; x1 = rotl32(x1, 13); x1 ^= x0;
  x0 += x1; x1 = rotl32(x1, 15); x1 ^= x0;
  x0 += x1; x1 = rotl32(x1, 26); x1 ^= x0;
  x0 += x1; x1 = rotl32(x1, 6);  x1 ^= x0;
  x0 += ks2; x1 += k0 + 5u;
  o0 = x0; o1 = x1;
}

__device__ __forceinline__ uint32_t jax_randbits(uint32_t k0, uint32_t k1,
                                                 uint32_t e, uint32_t size) {
#if JAX_PARTITIONABLE
  (void)size;
  uint32_t o0, o1;
  threefry2x32(k0, k1, 0u, e, o0, o1);
  return o0 ^ o1;
#else
  const uint32_t half = size >> 1;
  uint32_t o0, o1;
  if (e < half) { threefry2x32(k0, k1, e, e + half, o0, o1); return o0; }
  threefry2x32(k0, k1, e - half, e, o0, o1); return o1;
#endif
}

// exact f32 replication of jax.random.uniform(minval=1e-10, maxval=1.0)
__device__ __forceinline__ float bits_to_unif(uint32_t bits) {
  float f = __uint_as_float((bits >> 9) | 0x3f800000u) - 1.0f;
  return fmaxf(1e-10f, f + 1e-10f);
}

// ---------------------------------------------------------------- helpers
__device__ __forceinline__ double wave_sum_f64(double x) {
#pragma unroll
  for (int off = 32; off > 0; off >>= 1) x += __shfl_xor(x, off);
  return x;
}

__device__ __forceinline__ void argmax_gap6(const double* s, int& arg, double& gap) {
  int a = 0;
#pragma unroll
  for (int j = 1; j < 6; ++j) if (s[j] > s[a]) a = j;
  double second = -1e300;
#pragma unroll
  for (int j = 0; j < 6; ++j) if (j != a && s[j] > second) second = s[j];
  arg = a; gap = s[a] - second;
}

__device__ __forceinline__ float idx_to_bits(int i) {
  return (float)((i < 4) ? 2 * (i + 1) : (i == 4 ? 12 : 16));
}

// ---------------------------------------------------------------- K0: ss + keys
__global__ void k0_setup(const float* __restrict__ sy, const float* __restrict__ sH,
                         const float* __restrict__ sd, float* __restrict__ ss,
                         uint32_t* __restrict__ keys) {
  const int t = threadIdx.x;
  if (t < 18) {
    const int tensor = t / 6, i = t % 6;
    const int qp_[6] = {1, 7, 31, 127, 2047, 32767};
    const long long sizes[3] = {262144LL, 16777216LL, 2097152LL};  // y, H, v
    const float* sarr = tensor == 0 ? sy : (tensor == 1 ? sH : sd);
    const double g64 = 1.0 / sqrt((double)(sizes[tensor] * (long long)qp_[i]));
    const float g32 = (float)g64;
    const float s = sarr[i];
    const float t1 = s * g32;
    ss[t] = t1 + (s - t1);  // _grad_scale forward, exact f32 sequence
  }
#if JAX_PARTITIONABLE
  if (t >= 32 && t < 35) {
    uint32_t o0, o1;
    threefry2x32(0u, 42u, 0u, (uint32_t)(t - 32), o0, o1);
    keys[(t - 32) * 2 + 0] = o0;
    keys[(t - 32) * 2 + 1] = o1;
  }
#else
  if (t == 32) {
    uint32_t a0, b0, a1, b1, a2, b2;
    threefry2x32(0u, 42u, 0u, 3u, a0, b0);
    threefry2x32(0u, 42u, 1u, 4u, a1, b1);
    threefry2x32(0u, 42u, 2u, 5u, a2, b2);
    keys[0] = a0; keys[1] = a1;
    keys[2] = a2; keys[3] = b0;
    keys[4] = b1; keys[5] = b2;
  }
#endif
}

// ---------------------------------------------------------------- K1: hp_mean
__global__ __launch_bounds__(128) void k1a_hpower_partial(
    const float* __restrict__ Hm, double* __restrict__ partial) {
  const int blk = blockIdx.x;       // 512 = 64 b * 8 l-chunks
  const int b = blk >> 3, lc = blk & 7;
  const int t = threadIdx.x;        // 128 = (k,c)
  const float* base = Hm + (size_t)(b * 256 + lc * 32) * 1024;
  double acc = 0.0;
  for (int l = 0; l < 32; ++l) {
#pragma unroll
    for (int n = 0; n < 8; ++n) {
      const float x = base[(size_t)l * 1024 + n * 128 + t];
      acc = fma((double)x, (double)x, acc);
    }
  }
  const double other = __shfl_xor(acc, 1);
  if ((t & 1) == 0) partial[(size_t)blk * 64 + (t >> 1)] = acc + other;
}

__global__ void k1b_hpmean(const double* __restrict__ partial,
                           double* __restrict__ hp_mean) {
  const int id = blockIdx.x * blockDim.x + threadIdx.x;  // 4096 = b*64+k
  if (id >= 4096) return;
  const int b = id >> 6, k = id & 63;
  double s = 0.0;
#pragma unroll
  for (int lc = 0; lc < 8; ++lc) s += partial[(size_t)(b * 8 + lc) * 64 + k];
  hp_mean[id] = s * (1.0 / 256.0);
}

// ---------------------------------------------------------------- K2: main
// ONE m per 256-thread block (4 waves x 16 output rows); grid = 16384.
// In-place column-major swizzled act buffer; scalar-pipe weights.
__global__ __launch_bounds__(256, 4) void k2_main(
    const float* __restrict__ v, const float* __restrict__ Hm,
    const float* __restrict__ y, const float* __restrict__ snr,
    const float* __restrict__ w1, const float* __restrict__ b1,
    const float* __restrict__ w2, const float* __restrict__ b2,
    const float* __restrict__ w3, const float* __restrict__ b3,
    const float* __restrict__ wy, const float* __restrict__ by,
    const float* __restrict__ wh, const float* __restrict__ bh,
    const float* __restrict__ wd, const float* __restrict__ bd,
    const double* __restrict__ hp_mean, const uint32_t* __restrict__ keys,
    float* __restrict__ out) {
  const int t = threadIdx.x;
  const int lane = t & 63;
  const int wvx = t >> 6;
  const int m = blockIdx.x;
  const int j0 = wvx * 16;  // this wave's output-row block

  __shared__ __align__(16) float hbuf[4096];   // 16KB act, col-major swizzled
  __shared__ __align__(16) float headP[1280];  // [k][20]

  // ---- phase A/B: wave 0 computes f64 features (op order identical to R9)
  if (wvx == 0) {
    const float2* Hp = (const float2*)Hm + (size_t)m * 512;
    double aw[4];
#pragma unroll
    for (int w = 0; w < 4; ++w) {
      double acc = 0.0;
#pragma unroll
      for (int nn = 0; nn < 2; ++nn) {
        const float2 h2v = Hp[(2 * w + nn) * 64 + lane];
        acc = fma((double)h2v.x, (double)h2v.x, acc);
        acc = fma((double)h2v.y, (double)h2v.y, acc);
      }
      aw[w] = acc;
    }
    const double hp = ((aw[0] + aw[1]) + aw[2]) + aw[3];
    const double tp = wave_sum_f64(hp);
    double ypart = 0.0;
    if (lane < 16) { const double yv = (double)y[m * 16 + lane]; ypart = yv * yv; }
    const double yp = wave_sum_f64(ypart);
    const float2 vv = ((const float2*)v)[m * 64 + lane];
    const float snrv = snr[m * 64 + lane];
    const double hpm = hp_mean[(m >> 8) * 64 + lane];
    float f[9];
    f[0] = (float)vv.x;
    f[1] = (float)vv.y;
    f[2] = snrv;
    f[3] = (float)hp;
    f[4] = (float)hpm;
    f[5] = (float)log1p(hp / ((tp - hp) + 1e-10));
    f[6] = (float)log1p(tp);
    f[7] = (float)log1p(yp);
    f[8] = (float)sqrt(fma((double)vv.x, (double)vv.x,
                           fma((double)vv.y, (double)vv.y, 1e-10)));
    float4 w0; w0.x = f[0]; w0.y = f[1]; w0.z = f[2]; w0.w = f[3];
    float4 w1v; w1v.x = f[4]; w1v.y = f[5]; w1v.z = f[6]; w1v.w = f[7];
    float4 w2v; w2v.x = f[8]; w2v.y = 0.0f; w2v.z = 0.0f; w2v.w = 0.0f;
    *(float4*)&hbuf[HOFF(lane, 0)] = w0;
    *(float4*)&hbuf[HOFF(lane, 1)] = w1v;
    *(float4*)&hbuf[HOFF(lane, 2)] = w2v;
  }
  __syncthreads();

  // ---- L1: 9 -> 64; each wave computes rows j0..j0+15 for its lane's column
  {
    const float4 c0 = *(const float4*)&hbuf[HOFF(lane, 0)];
    const float4 c1 = *(const float4*)&hbuf[HOFF(lane, 1)];
    const float4 c2 = *(const float4*)&hbuf[HOFF(lane, 2)];
    const float fx[9] = {c0.x, c0.y, c0.z, c0.w, c1.x, c1.y, c1.z, c1.w, c2.x};
    float a[16];
#pragma unroll
    for (int q = 0; q < 16; ++q) a[q] = b1[j0 + q];
#pragma unroll
    for (int i = 0; i < 9; ++i) {
      const float xi = fx[i];
#pragma unroll
      for (int q = 0; q < 16; ++q)
        a[q] = fmaf(w1[(j0 + q) * 9 + i], xi, a[q]);
    }
    __syncthreads();  // all f reads done before rows 0..15 overwritten
#pragma unroll
    for (int cc = 0; cc < 4; ++cc) {
      float4 r;
      r.x = fmaxf(a[cc * 4 + 0], 0.0f);
      r.y = fmaxf(a[cc * 4 + 1], 0.0f);
      r.z = fmaxf(a[cc * 4 + 2], 0.0f);
      r.w = fmaxf(a[cc * 4 + 3], 0.0f);
      *(float4*)&hbuf[HOFF(lane, 4 * wvx + cc)] = r;
    }
  }
  __syncthreads();

  // ---- L2 / L3: 64 -> 64, in-place, read-all -> barrier -> write ----
  const float* Ws[2] = {w2, w3};
  const float* Bs[2] = {b2, b3};
#pragma unroll 1
  for (int layer = 0; layer < 2; ++layer) {
    const float* __restrict__ W = Ws[layer];
    const float* __restrict__ B = Bs[layer];
    float a[16];
#pragma unroll
    for (int q = 0; q < 16; ++q) a[q] = B[j0 + q];
#pragma unroll
    for (int c = 0; c < 16; ++c) {
      const float4 x4 = *(const float4*)&hbuf[HOFF(lane, c)];
      const float xe[4] = {x4.x, x4.y, x4.z, x4.w};
#pragma unroll
      for (int e = 0; e < 4; ++e) {
        const float xi = xe[e];
        const int i = 4 * c + e;
#pragma unroll
        for (int q = 0; q < 16; ++q)
          a[q] = fmaf(W[(j0 + q) * 64 + i], xi, a[q]);
      }
    }
    __syncthreads();  // all reads of this layer done before in-place write
#pragma unroll
    for (int cc = 0; cc < 4; ++cc) {
      float4 r;
      r.x = fmaxf(a[cc * 4 + 0], 0.0f);
      r.y = fmaxf(a[cc * 4 + 1], 0.0f);
      r.z = fmaxf(a[cc * 4 + 2], 0.0f);
      r.w = fmaxf(a[cc * 4 + 3], 0.0f);
      *(float4*)&hbuf[HOFF(lane, 4 * wvx + cc)] = r;
    }
    __syncthreads();
  }

  // ---- heads: 18 rows, 5 per wave (r = wvx + 4q), R5 row split ----
  {
    const float* Wr[5];
    float a5[5];
#pragma unroll
    for (int q = 0; q < 5; ++q) {
      const int r = wvx + 4 * q;
      Wr[q] = (r < 6) ? wy + r * 64
            : (r < 12) ? wh + (r - 6) * 64
            : (r < 18) ? wd + (r - 12) * 64 : wy;
      a5[q] = (r < 6) ? by[r] : (r < 12) ? bh[r - 6] : (r < 18) ? bd[r - 12] : 0.0f;
    }
#pragma unroll
    for (int c = 0; c < 16; ++c) {
      const float4 x4 = *(const float4*)&hbuf[HOFF(lane, c)];
      const float xe[4] = {x4.x, x4.y, x4.z, x4.w};
#pragma unroll
      for (int e = 0; e < 4; ++e) {
        const float xi = xe[e];
        const int i = 4 * c + e;
#pragma unroll
        for (int q = 0; q < 5; ++q)
          a5[q] = fmaf(xi, Wr[q][i], a5[q]);
      }
    }
#pragma unroll
    for (int q = 0; q < 5; ++q) {
      const int r = wvx + 4 * q;
      if (r < 18) headP[lane * 20 + r] = a5[q];
    }
  }
  __syncthreads();

  if (wvx != 0) return;  // after the final barrier — legal

  // ---- phase C: selection (verbatim R9), wave 0, lane = k ----
  const int k = lane;
  float ly[6], lh[6], ld[6];
#pragma unroll
  for (int j = 0; j < 6; ++j) {
    ly[j] = headP[k * 20 + j];
    lh[j] = headP[k * 20 + 6 + j];
    ld[j] = headP[k * 20 + 12 + j];
  }

  const uint32_t g1k0 = keys[0], g1k1 = keys[1];
  const uint32_t g2k0 = keys[2], g2k1 = keys[3];
  const uint32_t g3k0 = keys[4], g3k1 = keys[5];

  double sH[6], sD[6];
  const uint32_t eH = (uint32_t)(m * 64 + k) * 6u;
#pragma unroll
  for (int j = 0; j < 6; ++j) {
    const float u = bits_to_unif(jax_randbits(g2k0, g2k1, eH + j, 6291456u));
    sH[j] = (double)lh[j] + (double)(-logf(-logf(u)));
  }
#pragma unroll
  for (int j = 0; j < 6; ++j) {
    const float u = bits_to_unif(jax_randbits(g3k0, g3k1, eH + j, 6291456u));
    sD[j] = (double)ld[j] + (double)(-logf(-logf(u)));
  }
  int argH, argD; double gapH, gapD;
  argmax_gap6(sH, argH, gapH);
  argmax_gap6(sD, argD, gapD);

  double lysum[6];
#pragma unroll
  for (int j = 0; j < 6; ++j) lysum[j] = wave_sum_f64((double)ly[j]);

  int argY = 0; double gapY = 1e30;
  if (k == 0) {
    double sY[6];
#pragma unroll
    for (int j = 0; j < 6; ++j) {
      const float u = bits_to_unif(jax_randbits(g1k0, g1k1, (uint32_t)(m * 6 + j), 98304u));
      sY[j] = lysum[j] * (1.0 / 64.0) - log(-log((double)u));
    }
    argmax_gap6(sY, argY, gapY);
  }
  const int needY = __shfl((k == 0 && gapY < MARGIN_THETA) ? 1 : 0, 0);
  const bool fH = gapH < MARGIN_THETA;
  const bool fD = gapD < MARGIN_THETA;

  uint8_t* flags = (uint8_t*)(out + O_vq);
  flags[F_SAMPLE + (size_t)m * 64 + k] = (uint8_t)((fH ? 1 : 0) | (fD ? 2 : 0));
  const bool anyHD = __ballot(fH || fD) != 0ull;
  if (k == 0)
    flags[F_M + m] = (uint8_t)(((anyHD || needY) ? 1 : 0) | (needY ? 2 : 0));

  argY = __shfl(argY, 0);

  const float bY = 16.0f * idx_to_bits(argY);   // 2*N*bits
  const float bH = 16.0f * idx_to_bits(argH);
  const float bD = 2.0f * idx_to_bits(argD);

  if (k == 0) {
    out[O_yba + m] = bY;
#pragma unroll
    for (int j = 0; j < 6; ++j) out[O_wy + m * 6 + j] = (j == argY) ? 1.0f : 0.0f;
  }
  out[O_Hbl + (size_t)m * 64 + k] = bH;
  out[O_dbl + (size_t)m * 64 + k] = bD;
  out[O_eb + (size_t)m * 64 + k] = (bY * 0.015625f + bH) + bD;
#pragma unroll
  for (int j = 0; j < 6; ++j) {
    out[O_wH + (size_t)(m * 64 + k) * 6 + j] = (j == argH) ? 1.0f : 0.0f;
    out[O_wd + (size_t)(m * 64 + k) * 6 + j] = (j == argD) ? 1.0f : 0.0f;
  }
}

// ---------------------------------------------------------------- f64 helpers
// f64 variant for kfix: weights f32 in LDS (exact convert), act f64 [i][k].
template <int NI>
__device__ __forceinline__ void gemm64_f64(const double* __restrict__ inT,
                                           const float* __restrict__ WT,
                                           const float* __restrict__ bias,
                                           double* __restrict__ outT, int t) {
  const int k0 = (t & 15) * 4;
  const int j0 = (t >> 4) * 4;
  double acc[16];
#pragma unroll
  for (int jj = 0; jj < 4; ++jj) {
    const double bj = (double)bias[j0 + jj];
#pragma unroll
    for (int kk = 0; kk < 4; ++kk) acc[jj * 4 + kk] = bj;
  }
#pragma unroll 8
  for (int i = 0; i < NI; ++i) {
    const double x0 = inT[i * 68 + k0 + 0];
    const double x1 = inT[i * 68 + k0 + 1];
    const double x2 = inT[i * 68 + k0 + 2];
    const double x3 = inT[i * 68 + k0 + 3];
    const float4 wf = *(const float4*)&WT[i * 64 + j0];
    const double w0 = (double)wf.x, w1 = (double)wf.y;
    const double w2 = (double)wf.z, w3 = (double)wf.w;
    acc[0]  = fma(w0, x0, acc[0]);
    acc[1]  = fma(w0, x1, acc[1]);
    acc[2]  = fma(w0, x2, acc[2]);
    acc[3]  = fma(w0, x3, acc[3]);
    acc[4]  = fma(w1, x0, acc[4]);
    acc[5]  = fma(w1, x1, acc[5]);
    acc[6]  = fma(w1, x2, acc[6]);
    acc[7]  = fma(w1, x3, acc[7]);
    acc[8]  = fma(w2, x0, acc[8]);
    acc[9]  = fma(w2, x1, acc[9]);
    acc[10] = fma(w2, x2, acc[10]);
    acc[11] = fma(w2, x3, acc[11]);
    acc[12] = fma(w3, x0, acc[12]);
    acc[13] = fma(w3, x1, acc[13]);
    acc[14] = fma(w3, x2, acc[14]);
    acc[15] = fma(w3, x3, acc[15]);
  }
#pragma unroll
  for (int jj = 0; jj < 4; ++jj) {
#pragma unroll
    for (int kk = 0; kk < 4; ++kk) {
      const double a = acc[jj * 4 + kk];
      outT[(j0 + jj) * 68 + k0 + kk] = a > 0.0 ? a : 0.0;  // same relu as ref
    }
  }
}

__device__ __forceinline__ void heads20_f64(const double* __restrict__ actT,
                                            const float* __restrict__ whT,
                                            const float* __restrict__ by,
                                            const float* __restrict__ bh,
                                            const float* __restrict__ bd,
                                            double* __restrict__ headP, int t) {
  const int k = t & 63, w = t >> 6;
  double acc[5];
#pragma unroll
  for (int q = 0; q < 5; ++q) {
    const int r = w + 4 * q;
    acc[q] = (r < 6) ? (double)by[r]
           : (r < 12) ? (double)bh[r - 6]
           : (r < 18) ? (double)bd[r - 12] : 0.0;
  }
#pragma unroll 8
  for (int i = 0; i < 64; ++i) {
    const double x = actT[i * 68 + k];
#pragma unroll
    for (int q = 0; q < 5; ++q)
      acc[q] = fma(x, (double)whT[(w + 4 * q) * 64 + i], acc[q]);
  }
#pragma unroll
  for (int q = 0; q < 5; ++q) {
    const int r = w + 4 * q;
    if (r < 18) headP[k * 20 + r] = acc[q];
  }
}

// ---------------------------------------------------------------- kfix
// 256-thread block handles 8 m's; per flagged m runs the f64 LDS-gemm MLP.
__global__ __launch_bounds__(256, 1) void kfix(
    const float* __restrict__ v, const float* __restrict__ Hm,
    const float* __restrict__ y, const float* __restrict__ snr,
    const float* __restrict__ w1, const float* __restrict__ b1,
    const float* __restrict__ w2, const float* __restrict__ b2,
    const float* __restrict__ w3, const float* __restrict__ b3,
    const float* __restrict__ wy, const float* __restrict__ by,
    const float* __restrict__ wh, const float* __restrict__ bh,
    const float* __restrict__ wd, const float* __restrict__ bd,
    const double* __restrict__ hp_mean, const uint32_t* __restrict__ keys,
    float* __restrict__ out) {
  const int t = threadIdx.x;
  const int lane = t & 63;
  const int wvx = t >> 6;
  const int m0 = blockIdx.x * 8;
  const uint8_t* flags = (const uint8_t*)(out + O_vq);

  __shared__ uint32_t mfs[8];
  __shared__ __align__(32) char smem[120064];
  float*  w1T     = (float*)smem;                 // 576 f  [i<9][j]
  float*  w2T     = (float*)(smem + 2304);        // 4096 f [i][j]
  float*  w3T     = (float*)(smem + 18688);       // 4096 f [i][j]
  float*  whT     = (float*)(smem + 35072);       // 1280 f [r<20][i]
  double* actA64  = (double*)(smem + 40192);      // 64x68 d [row][k]
  double* actB64  = (double*)(smem + 75008);      // 64x68 d
  double* headP64 = (double*)(smem + 109824);     // 64x20 d [k][20]
  double* hp4     = actB64;                       // alias (pre-L1 only)

  if (t < 8) mfs[t] = flags[F_M + m0 + t];
  __syncthreads();
  bool any = false;
#pragma unroll
  for (int i = 0; i < 8; ++i) any |= (mfs[i] != 0);
  if (!any) return;

  // stage weights once (same transposed layouts as R5)
  for (int idx = t; idx < 576; idx += 256) {
    const int i = idx >> 6, j = idx & 63;
    w1T[idx] = w1[j * 9 + i];
  }
  for (int idx = t; idx < 4096; idx += 256) {
    const int i = idx >> 6, j = idx & 63;
    w2T[idx] = w2[j * 64 + i];
    w3T[idx] = w3[j * 64 + i];
  }
  for (int idx = t; idx < 1280; idx += 256) {
    const int r = idx >> 6, i = idx & 63;
    whT[idx] = (r < 6) ? wy[r * 64 + i]
             : (r < 12) ? wh[(r - 6) * 64 + i]
             : (r < 18) ? wd[(r - 12) * 64 + i] : 0.0f;
  }

#pragma unroll 1
  for (int mi = 0; mi < 8; ++mi) {
    const uint32_t mf = mfs[mi];
    if (mf == 0) continue;  // block-uniform
    const int m = m0 + mi;

    // hp partials, identical op order to k2
    {
      const float2* Hp = (const float2*)Hm + (size_t)m * 512;
      double acc = 0.0;
#pragma unroll
      for (int nn = 0; nn < 2; ++nn) {
        const float2 h2v = Hp[(2 * wvx + nn) * 64 + lane];
        acc = fma((double)h2v.x, (double)h2v.x, acc);
        acc = fma((double)h2v.y, (double)h2v.y, acc);
      }
      __syncthreads();  // weights staged / prior-m reads done before actB reuse
      hp4[wvx * 64 + lane] = acc;
    }
    __syncthreads();

    // wave 0: f64 features -> actA64 rows 0..8
    if (t < 64) {
      const double hp = ((hp4[lane] + hp4[64 + lane]) + hp4[128 + lane]) + hp4[192 + lane];
      const double tp = wave_sum_f64(hp);
      double ypart = 0.0;
      if (lane < 16) { const double yv = (double)y[m * 16 + lane]; ypart = yv * yv; }
      const double yp = wave_sum_f64(ypart);
      const float2 vv = ((const float2*)v)[m * 64 + lane];
      const float snrv = snr[m * 64 + lane];
      const double hpm = hp_mean[(m >> 8) * 64 + lane];
      double f[9];
      f[0] = (double)vv.x;
      f[1] = (double)vv.y;
      f[2] = (double)snrv;
      f[3] = hp;
      f[4] = hpm;
      f[5] = log1p(hp / ((tp - hp) + 1e-10));
      f[6] = log1p(tp);
      f[7] = log1p(yp);
      f[8] = sqrt(fma((double)vv.x, (double)vv.x,
                      fma((double)vv.y, (double)vv.y, 1e-10)));
#pragma unroll
      for (int i = 0; i < 9; ++i) actA64[i * 68 + lane] = f[i];
    }
    __syncthreads();

    gemm64_f64<9>(actA64, w1T, b1, actB64, t);
    __syncthreads();
    gemm64_f64<64>(actB64, w2T, b2, actA64, t);
    __syncthreads();
    gemm64_f64<64>(actA64, w3T, b3, actB64, t);
    __syncthreads();
    heads20_f64(actB64, whT, by, bh, bd, headP64, t);
    __syncthreads();

    // wave 0: refine flagged selections
    if (t < 64) {
      const int k = lane;
      const uint8_t f = flags[F_SAMPLE + (size_t)m * 64 + k];
      double lyd[6], lhd[6], ldd[6];
#pragma unroll
      for (int j = 0; j < 6; ++j) {
        lyd[j] = headP64[k * 20 + j];
        lhd[j] = headP64[k * 20 + 6 + j];
        ldd[j] = headP64[k * 20 + 12 + j];
      }
      const uint32_t g1k0 = keys[0], g1k1 = keys[1];
      const uint32_t g2k0 = keys[2], g2k1 = keys[3];
      const uint32_t g3k0 = keys[4], g3k1 = keys[5];
      const uint32_t eH = (uint32_t)(m * 64 + k) * 6u;

      float bHf, bDf;
      if (f & 1) {
        double s2[6];
#pragma unroll
        for (int j = 0; j < 6; ++j) {
          const float u = bits_to_unif(jax_randbits(g2k0, g2k1, eH + j, 6291456u));
          s2[j] = lhd[j] - log(-log((double)u));
        }
        int argH; double g; argmax_gap6(s2, argH, g);
        bHf = 16.0f * idx_to_bits(argH);
        out[O_Hbl + (size_t)m * 64 + k] = bHf;
#pragma unroll
        for (int j = 0; j < 6; ++j)
          out[O_wH + (size_t)(m * 64 + k) * 6 + j] = (j == argH) ? 1.0f : 0.0f;
      } else {
        bHf = out[O_Hbl + (size_t)m * 64 + k];
      }
      if (f & 2) {
        double s2[6];
#pragma unroll
        for (int j = 0; j < 6; ++j) {
          const float u = bits_to_unif(jax_randbits(g3k0, g3k1, eH + j, 6291456u));
          s2[j] = ldd[j] - log(-log((double)u));
        }
        int argD; double g; argmax_gap6(s2, argD, g);
        bDf = 2.0f * idx_to_bits(argD);
        out[O_dbl + (size_t)m * 64 + k] = bDf;
#pragma unroll
        for (int j = 0; j < 6; ++j)
          out[O_wd + (size_t)(m * 64 + k) * 6 + j] = (j == argD) ? 1.0f : 0.0f;
      } else {
        bDf = out[O_dbl + (size_t)m * 64 + k];
      }

      float bYf;
      if (mf & 2) {
        double lys2[6];
#pragma unroll
        for (int j = 0; j < 6; ++j) lys2[j] = wave_sum_f64(lyd[j]);
        int argY = 0;
        if (k == 0) {
          double s2[6];
#pragma unroll
          for (int j = 0; j < 6; ++j) {
            const float u = bits_to_unif(jax_randbits(g1k0, g1k1, (uint32_t)(m * 6 + j), 98304u));
            s2[j] = lys2[j] * (1.0 / 64.0) - log(-log((double)u));
          }
          double g; argmax_gap6(s2, argY, g);
        }
        argY = __shfl(argY, 0);
        bYf = 16.0f * idx_to_bits(argY);
        if (k == 0) {
          out[O_yba + m] = bYf;
#pragma unroll
          for (int j = 0; j < 6; ++j) out[O_wy + m * 6 + j] = (j == argY) ? 1.0f : 0.0f;
        }
      } else {
        bYf = out[O_yba + m];
      }

      out[O_eb + (size_t)m * 64 + k] = (bYf * 0.015625f + bHf) + bDf;
    }
    __syncthreads();  // headP64/actB64 safe before next mi reuses them
  }
}

// ---------------------------------------------------------------- LSQ quant
__device__ __forceinline__ int bits_to_idx(int bits) {
  return (bits <= 8) ? ((bits >> 1) - 1) : ((bits == 12) ? 4 : 5);
}

__device__ __forceinline__ float lsq1(float x, float ssv, float qn, float qp) {
  float t = x / ssv;
  t = fminf(fmaxf(t, qn), qp);
  return rintf(t) * ssv;
}

__global__ void k3_Hq(const float* __restrict__ Hm, const float* __restrict__ ss,
                      const float* __restrict__ Hbits, float* __restrict__ outHq) {
  const int id = blockIdx.x * blockDim.x + threadIdx.x;
  if (id >= 8388608) return;
  const int k = id & 63;
  const int m = id >> 9;
  const int bits = (int)Hbits[(size_t)m * 64 + k] >> 4;
  const int i = bits_to_idx(bits);
  const float ssv = ss[6 + i];
  const float qp = (float)((1 << (bits - 1)) - 1);
  const float qn = -(float)(1 << (bits - 1));
  const float2 x = ((const float2*)Hm)[id];
  float2 o;
  o.x = lsq1(x.x, ssv, qn, qp);
  o.y = lsq1(x.y, ssv, qn, qp);
  ((float2*)outHq)[id] = o;
}

__global__ void k4_vq(const float* __restrict__ v, const float* __restrict__ ss,
                      const float* __restrict__ dbits, float* __restrict__ outvq) {
  const int id = blockIdx.x * blockDim.x + threadIdx.x;
  if (id >= 1048576) return;
  const int bits = (int)dbits[id] >> 1;
  const int i = bits_to_idx(bits);
  const float ssv = ss[12 + i];
  const float qp = (float)((1 << (bits - 1)) - 1);
  const float qn = -(float)(1 << (bits - 1));
  const float2 x = ((const float2*)v)[id];
  float2 o;
  o.x = lsq1(x.x, ssv, qn, qp);
  o.y = lsq1(x.y, ssv, qn, qp);
  ((float2*)outvq)[id] = o;
}

__global__ void k5_yq(const float* __restrict__ y, const float* __restrict__ ss,
                      const float* __restrict__ ybits, float* __restrict__ outyq) {
  const int id = blockIdx.x * blockDim.x + threadIdx.x;
  if (id >= 131072) return;
  const int m = id >> 3;
  const int bits = (int)ybits[m] >> 4;
  const int i = bits_to_idx(bits);
  const float ssv = ss[i];
  const float qp = (float)((1 << (bits - 1)) - 1);
  const float qn = -(float)(1 << (bits - 1));
  const float2 x = ((const float2*)y)[id];
  float2 o;
  o.x = lsq1(x.x, ssv, qn, qp);
  o.y = lsq1(x.y, ssv, qn, qp);
  ((float2*)outyq)[id] = o;
}

// ---------------------------------------------------------------- launch
extern "C" void kernel_launch(void* const* d_in, const int* in_sizes, int n_in,
                              void* d_out, int out_size, void* d_ws, size_t ws_size,
                              hipStream_t stream) {
  const float* v   = (const float*)d_in[0];
  const float* Hm  = (const float*)d_in[1];
  const float* y   = (const float*)d_in[2];
  const float* snr = (const float*)d_in[3];
  const float* w1  = (const float*)d_in[4];
  const float* b1  = (const float*)d_in[5];
  const float* w2  = (const float*)d_in[6];
  const float* b2  = (const float*)d_in[7];
  const float* w3  = (const float*)d_in[8];
  const float* b3  = (const float*)d_in[9];
  const float* wy  = (const float*)d_in[10];
  const float* by  = (const float*)d_in[11];
  const float* wh  = (const float*)d_in[12];
  const float* bh  = (const float*)d_in[13];
  const float* wd  = (const float*)d_in[14];
  const float* bd  = (const float*)d_in[15];
  const float* sy  = (const float*)d_in[16];
  const float* sH  = (const float*)d_in[17];
  const float* sd  = (const float*)d_in[18];

  float* out = (float*)d_out;

  double* ws_partial = (double*)d_ws;
  double* ws_hpmean  = ws_partial + 32768;
  float*  ws_ss      = (float*)(ws_hpmean + 4096);
  uint32_t* ws_keys  = (uint32_t*)(ws_ss + 18);

  k0_setup<<<1, 64, 0, stream>>>(sy, sH, sd, ws_ss, ws_keys);
  k1a_hpower_partial<<<512, 128, 0, stream>>>(Hm, ws_partial);
  k1b_hpmean<<<16, 256, 0, stream>>>(ws_partial, ws_hpmean);
  k2_main<<<BL, 256, 0, stream>>>(v, Hm, y, snr, w1, b1, w2, b2, w3, b3,
                                  wy, by, wh, bh, wd, bd, ws_hpmean, ws_keys, out);
  kfix<<<BL / 8, 256, 0, stream>>>(v, Hm, y, snr, w1, b1, w2, b2, w3, b3,
                                   wy, by, wh, bh, wd, bd, ws_hpmean, ws_keys, out);
  k3_Hq<<<32768, 256, 0, stream>>>(Hm, ws_ss, out + O_Hbl, out + O_Hq);
  k4_vq<<<4096, 256, 0, stream>>>(v, ws_ss, out + O_dbl, out + O_vq);
  k5_yq<<<512, 256, 0, stream>>>(y, ws_ss, out + O_yba, out + O_yq);
}

// Round 6
// 2098.704 us; speedup vs baseline: 1.2525x; 1.2525x over previous
//
#include <hip/hip_runtime.h>
#include <cstdint>

// ============================================================================
// TripleAdaptiveQuantizerV10 — round 11: all-register scalar-weight MLP k2.
//
// R10 post-mortem: 4-wave split spilled to scratch (WRITE_SIZE 64MB->3.2GB,
// VALUBusy 16.7%) — runtime-indexed private arrays + widened unroll. Occupancy
// DID rise (42.7%) confirming the lever; spills drowned it. R11: back to the
// measured R9 structure (scalar-pipe weights, lane-owns-column, 1 wave/m,
// 597us, ~30% per-SIMD issue at 2.5 waves/SIMD) with ONE change: fully unroll
// both j and i in every layer so ALL indices are static -> h1/h2/h3[64] live
// in VGPRs, the 16KB LDS round-trip buffer is deleted (LDS=0). Peak pressure
// ~143 VGPR -> 3 waves/SIMD, no LDS occupancy cap, near-100% FMA stream with
// s_load weights (w[j*64+i] is SGPR-pointer + constant -> provably uniform).
// Features + phase C verbatim R9 -> ly/lh/ld bit-identical -> flags / kfix /
// outputs unchanged. Only k2 changed vs R9.
// ============================================================================

#define JAX_PARTITIONABLE 1

constexpr int BL = 64 * 256;  // 16384 (B*L)

// Output offsets (floats)
constexpr long long O_vq  = 0;
constexpr long long O_Hq  = 2097152;
constexpr long long O_yq  = 18874368;
constexpr long long O_eb  = 19136512;
constexpr long long O_wy  = 20185088;
constexpr long long O_wH  = 20283392;
constexpr long long O_wd  = 26574848;
constexpr long long O_yba = 32866304;
constexpr long long O_Hbl = 32882688;
constexpr long long O_dbl = 33931264;

// flag stash inside the v_q region (k4 overwrites all of v_q afterwards)
constexpr long long F_SAMPLE = 0;        // 1048576 bytes, 1 per (m,k)
constexpr long long F_M      = 1048576;  // 16384 bytes, 1 per m

#define MARGIN_THETA 3e-4

// ---------------------------------------------------------------- threefry
__device__ __forceinline__ uint32_t rotl32(uint32_t v, int d) {
  return (v << d) | (v >> (32 - d));
}

__device__ __forceinline__ void threefry2x32(uint32_t k0, uint32_t k1,
                                             uint32_t x0, uint32_t x1,
                                             uint32_t& o0, uint32_t& o1) {
  const uint32_t ks2 = k0 ^ k1 ^ 0x1BD11BDAu;
  x0 += k0; x1 += k1;
  x0 += x1; x1 = rotl32(x1, 13); x1 ^= x0;
  x0 += x1; x1 = rotl32(x1, 15); x1 ^= x0;
  x0 += x1; x1 = rotl32(x1, 26); x1 ^= x0;
  x0 += x1; x1 = rotl32(x1, 6);  x1 ^= x0;
  x0 += k1; x1 += ks2 + 1u;
  x0 += x1; x1 = rotl32(x1, 17); x1 ^= x0;
  x0 += x1; x1 = rotl32(x1, 29); x1 ^= x0;
  x0 += x1; x1 = rotl32(x1, 16); x1 ^= x0;
  x0 += x1; x1 = rotl32(x1, 24); x1 ^= x0;
  x0 += ks2; x1 += k0 + 2u;
  x0 += x1; x1 = rotl32(x1, 13); x1 ^= x0;
  x0 += x1; x1 = rotl32(x1, 15); x1 ^= x0;
  x0 += x1; x1 = rotl32(x1, 26); x1 ^= x0;
  x0 += x1; x1 = rotl32(x1, 6);  x1 ^= x0;
  x0 += k0; x1 += k1 + 3u;
  x0 += x1; x1 = rotl32(x1, 17); x1 ^= x0;
  x0 += x1; x1 = rotl32(x1, 29); x1 ^= x0;
  x0 += x1; x1 = rotl32(x1, 16); x1 ^= x0;
  x0 += x1; x1 = rotl32(x1, 24); x1 ^= x0;
  x0 += k1; x1 += ks2 + 4u;
  x0 += x1; x1 = rotl32(x1, 13); x1 ^= x0;
  x0 += x1; x1 = rotl32(x1, 15); x1 ^= x0;
  x0 += x1; x1 = rotl32(x1, 26); x1 ^= x0;
  x0 += x1; x1 = rotl32(x1, 6);  x1 ^= x0;
  x0 += ks2; x1 += k0 + 5u;
  o0 = x0; o1 = x1;
}

__device__ __forceinline__ uint32_t jax_randbits(uint32_t k0, uint32_t k1,
                                                 uint32_t e, uint32_t size) {
#if JAX_PARTITIONABLE
  (void)size;
  uint32_t o0, o1;
  threefry2x32(k0, k1, 0u, e, o0, o1);
  return o0 ^ o1;
#else
  const uint32_t half = size >> 1;
  uint32_t o0, o1;
  if (e < half) { threefry2x32(k0, k1, e, e + half, o0, o1); return o0; }
  threefry2x32(k0, k1, e - half, e, o0, o1); return o1;
#endif
}

// exact f32 replication of jax.random.uniform(minval=1e-10, maxval=1.0)
__device__ __forceinline__ float bits_to_unif(uint32_t bits) {
  float f = __uint_as_float((bits >> 9) | 0x3f800000u) - 1.0f;
  return fmaxf(1e-10f, f + 1e-10f);
}

// ---------------------------------------------------------------- helpers
__device__ __forceinline__ double wave_sum_f64(double x) {
#pragma unroll
  for (int off = 32; off > 0; off >>= 1) x += __shfl_xor(x, off);
  return x;
}

__device__ __forceinline__ void argmax_gap6(const double* s, int& arg, double& gap) {
  int a = 0;
#pragma unroll
  for (int j = 1; j < 6; ++j) if (s[j] > s[a]) a = j;
  double second = -1e300;
#pragma unroll
  for (int j = 0; j < 6; ++j) if (j != a && s[j] > second) second = s[j];
  arg = a; gap = s[a] - second;
}

__device__ __forceinline__ float idx_to_bits(int i) {
  return (float)((i < 4) ? 2 * (i + 1) : (i == 4 ? 12 : 16));
}

// ---------------------------------------------------------------- K0: ss + keys
__global__ void k0_setup(const float* __restrict__ sy, const float* __restrict__ sH,
                         const float* __restrict__ sd, float* __restrict__ ss,
                         uint32_t* __restrict__ keys) {
  const int t = threadIdx.x;
  if (t < 18) {
    const int tensor = t / 6, i = t % 6;
    const int qp_[6] = {1, 7, 31, 127, 2047, 32767};
    const long long sizes[3] = {262144LL, 16777216LL, 2097152LL};  // y, H, v
    const float* sarr = tensor == 0 ? sy : (tensor == 1 ? sH : sd);
    const double g64 = 1.0 / sqrt((double)(sizes[tensor] * (long long)qp_[i]));
    const float g32 = (float)g64;
    const float s = sarr[i];
    const float t1 = s * g32;
    ss[t] = t1 + (s - t1);  // _grad_scale forward, exact f32 sequence
  }
#if JAX_PARTITIONABLE
  if (t >= 32 && t < 35) {
    uint32_t o0, o1;
    threefry2x32(0u, 42u, 0u, (uint32_t)(t - 32), o0, o1);
    keys[(t - 32) * 2 + 0] = o0;
    keys[(t - 32) * 2 + 1] = o1;
  }
#else
  if (t == 32) {
    uint32_t a0, b0, a1, b1, a2, b2;
    threefry2x32(0u, 42u, 0u, 3u, a0, b0);
    threefry2x32(0u, 42u, 1u, 4u, a1, b1);
    threefry2x32(0u, 42u, 2u, 5u, a2, b2);
    keys[0] = a0; keys[1] = a1;
    keys[2] = a2; keys[3] = b0;
    keys[4] = b1; keys[5] = b2;
  }
#endif
}

// ---------------------------------------------------------------- K1: hp_mean
__global__ __launch_bounds__(128) void k1a_hpower_partial(
    const float* __restrict__ Hm, double* __restrict__ partial) {
  const int blk = blockIdx.x;       // 512 = 64 b * 8 l-chunks
  const int b = blk >> 3, lc = blk & 7;
  const int t = threadIdx.x;        // 128 = (k,c)
  const float* base = Hm + (size_t)(b * 256 + lc * 32) * 1024;
  double acc = 0.0;
  for (int l = 0; l < 32; ++l) {
#pragma unroll
    for (int n = 0; n < 8; ++n) {
      const float x = base[(size_t)l * 1024 + n * 128 + t];
      acc = fma((double)x, (double)x, acc);
    }
  }
  const double other = __shfl_xor(acc, 1);
  if ((t & 1) == 0) partial[(size_t)blk * 64 + (t >> 1)] = acc + other;
}

__global__ void k1b_hpmean(const double* __restrict__ partial,
                           double* __restrict__ hp_mean) {
  const int id = blockIdx.x * blockDim.x + threadIdx.x;  // 4096 = b*64+k
  if (id >= 4096) return;
  const int b = id >> 6, k = id & 63;
  double s = 0.0;
#pragma unroll
  for (int lc = 0; lc < 8; ++lc) s += partial[(size_t)(b * 8 + lc) * 64 + k];
  hp_mean[id] = s * (1.0 / 256.0);
}

// ---------------------------------------------------------------- K2: main
// ONE m per 64-thread (1-wave) block; lane = k. No barriers, NO LDS.
// Weights via scalar pipe (compile-time offsets off SGPR pointers);
// activations fully in VGPRs (all indices static via full unroll).
__global__ __launch_bounds__(64) void k2_main(
    const float* __restrict__ v, const float* __restrict__ Hm,
    const float* __restrict__ y, const float* __restrict__ snr,
    const float* __restrict__ w1, const float* __restrict__ b1,
    const float* __restrict__ w2, const float* __restrict__ b2,
    const float* __restrict__ w3, const float* __restrict__ b3,
    const float* __restrict__ wy, const float* __restrict__ by,
    const float* __restrict__ wh, const float* __restrict__ bh,
    const float* __restrict__ wd, const float* __restrict__ bd,
    const double* __restrict__ hp_mean, const uint32_t* __restrict__ keys,
    float* __restrict__ out) {
  const int lane = threadIdx.x;
  const int m = blockIdx.x;

  // ---- features (f64 op order identical to R9) ----
  float f[9];
  {
    const float2* Hp = (const float2*)Hm + (size_t)m * 512;
    double aw[4];
#pragma unroll
    for (int w = 0; w < 4; ++w) {
      double acc = 0.0;
#pragma unroll
      for (int nn = 0; nn < 2; ++nn) {
        const float2 h2v = Hp[(2 * w + nn) * 64 + lane];
        acc = fma((double)h2v.x, (double)h2v.x, acc);
        acc = fma((double)h2v.y, (double)h2v.y, acc);
      }
      aw[w] = acc;
    }
    const double hp = ((aw[0] + aw[1]) + aw[2]) + aw[3];
    const double tp = wave_sum_f64(hp);
    double ypart = 0.0;
    if (lane < 16) { const double yv = (double)y[m * 16 + lane]; ypart = yv * yv; }
    const double yp = wave_sum_f64(ypart);
    const float2 vv = ((const float2*)v)[m * 64 + lane];
    const float snrv = snr[m * 64 + lane];
    const double hpm = hp_mean[(m >> 8) * 64 + lane];
    f[0] = (float)vv.x;
    f[1] = (float)vv.y;
    f[2] = snrv;
    f[3] = (float)hp;
    f[4] = (float)hpm;
    f[5] = (float)log1p(hp / ((tp - hp) + 1e-10));
    f[6] = (float)log1p(tp);
    f[7] = (float)log1p(yp);
    f[8] = (float)sqrt(fma((double)vv.x, (double)vv.x,
                           fma((double)vv.y, (double)vv.y, 1e-10)));
  }

  // ---- L1: 9 -> 64, all static indices (w1 row-major [j][i<9], uniform) ----
  float h1[64];
#pragma unroll
  for (int j = 0; j < 64; ++j) {
    float a = b1[j];
#pragma unroll
    for (int i = 0; i < 9; ++i) a = fmaf(w1[j * 9 + i], f[i], a);
    h1[j] = fmaxf(a, 0.0f);
  }

  // ---- L2: 64 -> 64, fully unrolled, registers only ----
  float h2[64];
#pragma unroll
  for (int j = 0; j < 64; ++j) {
    float a = b2[j];
#pragma unroll
    for (int i = 0; i < 64; ++i) a = fmaf(w2[j * 64 + i], h1[i], a);
    h2[j] = fmaxf(a, 0.0f);
  }

  // ---- L3: 64 -> 64 ----
  float h3[64];
#pragma unroll
  for (int j = 0; j < 64; ++j) {
    float a = b3[j];
#pragma unroll
    for (int i = 0; i < 64; ++i) a = fmaf(w3[j * 64 + i], h2[i], a);
    h3[j] = fmaxf(a, 0.0f);
  }

  // ---- heads: 64 -> 6+6+6, registers (same chains as R9) ----
  float ly[6], lh[6], ld[6];
#pragma unroll
  for (int r = 0; r < 6; ++r) {
    float a = by[r];
#pragma unroll
    for (int i = 0; i < 64; ++i) a = fmaf(h3[i], wy[r * 64 + i], a);
    ly[r] = a;
  }
#pragma unroll
  for (int r = 0; r < 6; ++r) {
    float a = bh[r];
#pragma unroll
    for (int i = 0; i < 64; ++i) a = fmaf(h3[i], wh[r * 64 + i], a);
    lh[r] = a;
  }
#pragma unroll
  for (int r = 0; r < 6; ++r) {
    float a = bd[r];
#pragma unroll
    for (int i = 0; i < 64; ++i) a = fmaf(h3[i], wd[r * 64 + i], a);
    ld[r] = a;
  }

  // ---- phase C: selection (verbatim R9), lane = k ----
  const int k = lane;

  const uint32_t g1k0 = keys[0], g1k1 = keys[1];
  const uint32_t g2k0 = keys[2], g2k1 = keys[3];
  const uint32_t g3k0 = keys[4], g3k1 = keys[5];

  double sH[6], sD[6];
  const uint32_t eH = (uint32_t)(m * 64 + k) * 6u;
#pragma unroll
  for (int j = 0; j < 6; ++j) {
    const float u = bits_to_unif(jax_randbits(g2k0, g2k1, eH + j, 6291456u));
    sH[j] = (double)lh[j] + (double)(-logf(-logf(u)));
  }
#pragma unroll
  for (int j = 0; j < 6; ++j) {
    const float u = bits_to_unif(jax_randbits(g3k0, g3k1, eH + j, 6291456u));
    sD[j] = (double)ld[j] + (double)(-logf(-logf(u)));
  }
  int argH, argD; double gapH, gapD;
  argmax_gap6(sH, argH, gapH);
  argmax_gap6(sD, argD, gapD);

  double lysum[6];
#pragma unroll
  for (int j = 0; j < 6; ++j) lysum[j] = wave_sum_f64((double)ly[j]);

  int argY = 0; double gapY = 1e30;
  if (k == 0) {
    double sY[6];
#pragma unroll
    for (int j = 0; j < 6; ++j) {
      const float u = bits_to_unif(jax_randbits(g1k0, g1k1, (uint32_t)(m * 6 + j), 98304u));
      sY[j] = lysum[j] * (1.0 / 64.0) - log(-log((double)u));
    }
    argmax_gap6(sY, argY, gapY);
  }
  const int needY = __shfl((k == 0 && gapY < MARGIN_THETA) ? 1 : 0, 0);
  const bool fH = gapH < MARGIN_THETA;
  const bool fD = gapD < MARGIN_THETA;

  uint8_t* flags = (uint8_t*)(out + O_vq);
  flags[F_SAMPLE + (size_t)m * 64 + k] = (uint8_t)((fH ? 1 : 0) | (fD ? 2 : 0));
  const bool anyHD = __ballot(fH || fD) != 0ull;
  if (k == 0)
    flags[F_M + m] = (uint8_t)(((anyHD || needY) ? 1 : 0) | (needY ? 2 : 0));

  argY = __shfl(argY, 0);

  const float bY = 16.0f * idx_to_bits(argY);   // 2*N*bits
  const float bH = 16.0f * idx_to_bits(argH);
  const float bD = 2.0f * idx_to_bits(argD);

  if (k == 0) {
    out[O_yba + m] = bY;
#pragma unroll
    for (int j = 0; j < 6; ++j) out[O_wy + m * 6 + j] = (j == argY) ? 1.0f : 0.0f;
  }
  out[O_Hbl + (size_t)m * 64 + k] = bH;
  out[O_dbl + (size_t)m * 64 + k] = bD;
  out[O_eb + (size_t)m * 64 + k] = (bY * 0.015625f + bH) + bD;
#pragma unroll
  for (int j = 0; j < 6; ++j) {
    out[O_wH + (size_t)(m * 64 + k) * 6 + j] = (j == argH) ? 1.0f : 0.0f;
    out[O_wd + (size_t)(m * 64 + k) * 6 + j] = (j == argD) ? 1.0f : 0.0f;
  }
}

// ---------------------------------------------------------------- f64 helpers
// f64 variant for kfix: weights f32 in LDS (exact convert), act f64 [i][k].
template <int NI>
__device__ __forceinline__ void gemm64_f64(const double* __restrict__ inT,
                                           const float* __restrict__ WT,
                                           const float* __restrict__ bias,
                                           double* __restrict__ outT, int t) {
  const int k0 = (t & 15) * 4;
  const int j0 = (t >> 4) * 4;
  double acc[16];
#pragma unroll
  for (int jj = 0; jj < 4; ++jj) {
    const double bj = (double)bias[j0 + jj];
#pragma unroll
    for (int kk = 0; kk < 4; ++kk) acc[jj * 4 + kk] = bj;
  }
#pragma unroll 8
  for (int i = 0; i < NI; ++i) {
    const double x0 = inT[i * 68 + k0 + 0];
    const double x1 = inT[i * 68 + k0 + 1];
    const double x2 = inT[i * 68 + k0 + 2];
    const double x3 = inT[i * 68 + k0 + 3];
    const float4 wf = *(const float4*)&WT[i * 64 + j0];
    const double w0 = (double)wf.x, w1 = (double)wf.y;
    const double w2 = (double)wf.z, w3 = (double)wf.w;
    acc[0]  = fma(w0, x0, acc[0]);
    acc[1]  = fma(w0, x1, acc[1]);
    acc[2]  = fma(w0, x2, acc[2]);
    acc[3]  = fma(w0, x3, acc[3]);
    acc[4]  = fma(w1, x0, acc[4]);
    acc[5]  = fma(w1, x1, acc[5]);
    acc[6]  = fma(w1, x2, acc[6]);
    acc[7]  = fma(w1, x3, acc[7]);
    acc[8]  = fma(w2, x0, acc[8]);
    acc[9]  = fma(w2, x1, acc[9]);
    acc[10] = fma(w2, x2, acc[10]);
    acc[11] = fma(w2, x3, acc[11]);
    acc[12] = fma(w3, x0, acc[12]);
    acc[13] = fma(w3, x1, acc[13]);
    acc[14] = fma(w3, x2, acc[14]);
    acc[15] = fma(w3, x3, acc[15]);
  }
#pragma unroll
  for (int jj = 0; jj < 4; ++jj) {
#pragma unroll
    for (int kk = 0; kk < 4; ++kk) {
      const double a = acc[jj * 4 + kk];
      outT[(j0 + jj) * 68 + k0 + kk] = a > 0.0 ? a : 0.0;  // same relu as ref
    }
  }
}

__device__ __forceinline__ void heads20_f64(const double* __restrict__ actT,
                                            const float* __restrict__ whT,
                                            const float* __restrict__ by,
                                            const float* __restrict__ bh,
                                            const float* __restrict__ bd,
                                            double* __restrict__ headP, int t) {
  const int k = t & 63, w = t >> 6;
  double acc[5];
#pragma unroll
  for (int q = 0; q < 5; ++q) {
    const int r = w + 4 * q;
    acc[q] = (r < 6) ? (double)by[r]
           : (r < 12) ? (double)bh[r - 6]
           : (r < 18) ? (double)bd[r - 12] : 0.0;
  }
#pragma unroll 8
  for (int i = 0; i < 64; ++i) {
    const double x = actT[i * 68 + k];
#pragma unroll
    for (int q = 0; q < 5; ++q)
      acc[q] = fma(x, (double)whT[(w + 4 * q) * 64 + i], acc[q]);
  }
#pragma unroll
  for (int q = 0; q < 5; ++q) {
    const int r = w + 4 * q;
    if (r < 18) headP[k * 20 + r] = acc[q];
  }
}

// ---------------------------------------------------------------- kfix
// 256-thread block handles 8 m's; per flagged m runs the f64 LDS-gemm MLP.
__global__ __launch_bounds__(256, 1) void kfix(
    const float* __restrict__ v, const float* __restrict__ Hm,
    const float* __restrict__ y, const float* __restrict__ snr,
    const float* __restrict__ w1, const float* __restrict__ b1,
    const float* __restrict__ w2, const float* __restrict__ b2,
    const float* __restrict__ w3, const float* __restrict__ b3,
    const float* __restrict__ wy, const float* __restrict__ by,
    const float* __restrict__ wh, const float* __restrict__ bh,
    const float* __restrict__ wd, const float* __restrict__ bd,
    const double* __restrict__ hp_mean, const uint32_t* __restrict__ keys,
    float* __restrict__ out) {
  const int t = threadIdx.x;
  const int lane = t & 63;
  const int wvx = t >> 6;
  const int m0 = blockIdx.x * 8;
  const uint8_t* flags = (const uint8_t*)(out + O_vq);

  __shared__ uint32_t mfs[8];
  __shared__ __align__(32) char smem[120064];
  float*  w1T     = (float*)smem;                 // 576 f  [i<9][j]
  float*  w2T     = (float*)(smem + 2304);        // 4096 f [i][j]
  float*  w3T     = (float*)(smem + 18688);       // 4096 f [i][j]
  float*  whT     = (float*)(smem + 35072);       // 1280 f [r<20][i]
  double* actA64  = (double*)(smem + 40192);      // 64x68 d [row][k]
  double* actB64  = (double*)(smem + 75008);      // 64x68 d
  double* headP64 = (double*)(smem + 109824);     // 64x20 d [k][20]
  double* hp4     = actB64;                       // alias (pre-L1 only)

  if (t < 8) mfs[t] = flags[F_M + m0 + t];
  __syncthreads();
  bool any = false;
#pragma unroll
  for (int i = 0; i < 8; ++i) any |= (mfs[i] != 0);
  if (!any) return;

  // stage weights once (same transposed layouts as R5)
  for (int idx = t; idx < 576; idx += 256) {
    const int i = idx >> 6, j = idx & 63;
    w1T[idx] = w1[j * 9 + i];
  }
  for (int idx = t; idx < 4096; idx += 256) {
    const int i = idx >> 6, j = idx & 63;
    w2T[idx] = w2[j * 64 + i];
    w3T[idx] = w3[j * 64 + i];
  }
  for (int idx = t; idx < 1280; idx += 256) {
    const int r = idx >> 6, i = idx & 63;
    whT[idx] = (r < 6) ? wy[r * 64 + i]
             : (r < 12) ? wh[(r - 6) * 64 + i]
             : (r < 18) ? wd[(r - 12) * 64 + i] : 0.0f;
  }

#pragma unroll 1
  for (int mi = 0; mi < 8; ++mi) {
    const uint32_t mf = mfs[mi];
    if (mf == 0) continue;  // block-uniform
    const int m = m0 + mi;

    // hp partials, identical op order to k2
    {
      const float2* Hp = (const float2*)Hm + (size_t)m * 512;
      double acc = 0.0;
#pragma unroll
      for (int nn = 0; nn < 2; ++nn) {
        const float2 h2v = Hp[(2 * wvx + nn) * 64 + lane];
        acc = fma((double)h2v.x, (double)h2v.x, acc);
        acc = fma((double)h2v.y, (double)h2v.y, acc);
      }
      __syncthreads();  // weights staged / prior-m reads done before actB reuse
      hp4[wvx * 64 + lane] = acc;
    }
    __syncthreads();

    // wave 0: f64 features -> actA64 rows 0..8
    if (t < 64) {
      const double hp = ((hp4[lane] + hp4[64 + lane]) + hp4[128 + lane]) + hp4[192 + lane];
      const double tp = wave_sum_f64(hp);
      double ypart = 0.0;
      if (lane < 16) { const double yv = (double)y[m * 16 + lane]; ypart = yv * yv; }
      const double yp = wave_sum_f64(ypart);
      const float2 vv = ((const float2*)v)[m * 64 + lane];
      const float snrv = snr[m * 64 + lane];
      const double hpm = hp_mean[(m >> 8) * 64 + lane];
      double f[9];
      f[0] = (double)vv.x;
      f[1] = (double)vv.y;
      f[2] = (double)snrv;
      f[3] = hp;
      f[4] = hpm;
      f[5] = log1p(hp / ((tp - hp) + 1e-10));
      f[6] = log1p(tp);
      f[7] = log1p(yp);
      f[8] = sqrt(fma((double)vv.x, (double)vv.x,
                      fma((double)vv.y, (double)vv.y, 1e-10)));
#pragma unroll
      for (int i = 0; i < 9; ++i) actA64[i * 68 + lane] = f[i];
    }
    __syncthreads();

    gemm64_f64<9>(actA64, w1T, b1, actB64, t);
    __syncthreads();
    gemm64_f64<64>(actB64, w2T, b2, actA64, t);
    __syncthreads();
    gemm64_f64<64>(actA64, w3T, b3, actB64, t);
    __syncthreads();
    heads20_f64(actB64, whT, by, bh, bd, headP64, t);
    __syncthreads();

    // wave 0: refine flagged selections
    if (t < 64) {
      const int k = lane;
      const uint8_t f = flags[F_SAMPLE + (size_t)m * 64 + k];
      double lyd[6], lhd[6], ldd[6];
#pragma unroll
      for (int j = 0; j < 6; ++j) {
        lyd[j] = headP64[k * 20 + j];
        lhd[j] = headP64[k * 20 + 6 + j];
        ldd[j] = headP64[k * 20 + 12 + j];
      }
      const uint32_t g1k0 = keys[0], g1k1 = keys[1];
      const uint32_t g2k0 = keys[2], g2k1 = keys[3];
      const uint32_t g3k0 = keys[4], g3k1 = keys[5];
      const uint32_t eH = (uint32_t)(m * 64 + k) * 6u;

      float bHf, bDf;
      if (f & 1) {
        double s2[6];
#pragma unroll
        for (int j = 0; j < 6; ++j) {
          const float u = bits_to_unif(jax_randbits(g2k0, g2k1, eH + j, 6291456u));
          s2[j] = lhd[j] - log(-log((double)u));
        }
        int argH; double g; argmax_gap6(s2, argH, g);
        bHf = 16.0f * idx_to_bits(argH);
        out[O_Hbl + (size_t)m * 64 + k] = bHf;
#pragma unroll
        for (int j = 0; j < 6; ++j)
          out[O_wH + (size_t)(m * 64 + k) * 6 + j] = (j == argH) ? 1.0f : 0.0f;
      } else {
        bHf = out[O_Hbl + (size_t)m * 64 + k];
      }
      if (f & 2) {
        double s2[6];
#pragma unroll
        for (int j = 0; j < 6; ++j) {
          const float u = bits_to_unif(jax_randbits(g3k0, g3k1, eH + j, 6291456u));
          s2[j] = ldd[j] - log(-log((double)u));
        }
        int argD; double g; argmax_gap6(s2, argD, g);
        bDf = 2.0f * idx_to_bits(argD);
        out[O_dbl + (size_t)m * 64 + k] = bDf;
#pragma unroll
        for (int j = 0; j < 6; ++j)
          out[O_wd + (size_t)(m * 64 + k) * 6 + j] = (j == argD) ? 1.0f : 0.0f;
      } else {
        bDf = out[O_dbl + (size_t)m * 64 + k];
      }

      float bYf;
      if (mf & 2) {
        double lys2[6];
#pragma unroll
        for (int j = 0; j < 6; ++j) lys2[j] = wave_sum_f64(lyd[j]);
        int argY = 0;
        if (k == 0) {
          double s2[6];
#pragma unroll
          for (int j = 0; j < 6; ++j) {
            const float u = bits_to_unif(jax_randbits(g1k0, g1k1, (uint32_t)(m * 6 + j), 98304u));
            s2[j] = lys2[j] * (1.0 / 64.0) - log(-log((double)u));
          }
          double g; argmax_gap6(s2, argY, g);
        }
        argY = __shfl(argY, 0);
        bYf = 16.0f * idx_to_bits(argY);
        if (k == 0) {
          out[O_yba + m] = bYf;
#pragma unroll
          for (int j = 0; j < 6; ++j) out[O_wy + m * 6 + j] = (j == argY) ? 1.0f : 0.0f;
        }
      } else {
        bYf = out[O_yba + m];
      }

      out[O_eb + (size_t)m * 64 + k] = (bYf * 0.015625f + bHf) + bDf;
    }
    __syncthreads();  // headP64/actB64 safe before next mi reuses them
  }
}

// ---------------------------------------------------------------- LSQ quant
__device__ __forceinline__ int bits_to_idx(int bits) {
  return (bits <= 8) ? ((bits >> 1) - 1) : ((bits == 12) ? 4 : 5);
}

__device__ __forceinline__ float lsq1(float x, float ssv, float qn, float qp) {
  float t = x / ssv;
  t = fminf(fmaxf(t, qn), qp);
  return rintf(t) * ssv;
}

__global__ void k3_Hq(const float* __restrict__ Hm, const float* __restrict__ ss,
                      const float* __restrict__ Hbits, float* __restrict__ outHq) {
  const int id = blockIdx.x * blockDim.x + threadIdx.x;
  if (id >= 8388608) return;
  const int k = id & 63;
  const int m = id >> 9;
  const int bits = (int)Hbits[(size_t)m * 64 + k] >> 4;
  const int i = bits_to_idx(bits);
  const float ssv = ss[6 + i];
  const float qp = (float)((1 << (bits - 1)) - 1);
  const float qn = -(float)(1 << (bits - 1));
  const float2 x = ((const float2*)Hm)[id];
  float2 o;
  o.x = lsq1(x.x, ssv, qn, qp);
  o.y = lsq1(x.y, ssv, qn, qp);
  ((float2*)outHq)[id] = o;
}

__global__ void k4_vq(const float* __restrict__ v, const float* __restrict__ ss,
                      const float* __restrict__ dbits, float* __restrict__ outvq) {
  const int id = blockIdx.x * blockDim.x + threadIdx.x;
  if (id >= 1048576) return;
  const int bits = (int)dbits[id] >> 1;
  const int i = bits_to_idx(bits);
  const float ssv = ss[12 + i];
  const float qp = (float)((1 << (bits - 1)) - 1);
  const float qn = -(float)(1 << (bits - 1));
  const float2 x = ((const float2*)v)[id];
  float2 o;
  o.x = lsq1(x.x, ssv, qn, qp);
  o.y = lsq1(x.y, ssv, qn, qp);
  ((float2*)outvq)[id] = o;
}

__global__ void k5_yq(const float* __restrict__ y, const float* __restrict__ ss,
                      const float* __restrict__ ybits, float* __restrict__ outyq) {
  const int id = blockIdx.x * blockDim.x + threadIdx.x;
  if (id >= 131072) return;
  const int m = id >> 3;
  const int bits = (int)ybits[m] >> 4;
  const int i = bits_to_idx(bits);
  const float ssv = ss[i];
  const float qp = (float)((1 << (bits - 1)) - 1);
  const float qn = -(float)(1 << (bits - 1));
  const float2 x = ((const float2*)y)[id];
  float2 o;
  o.x = lsq1(x.x, ssv, qn, qp);
  o.y = lsq1(x.y, ssv, qn, qp);
  ((float2*)outyq)[id] = o;
}

// ---------------------------------------------------------------- launch
extern "C" void kernel_launch(void* const* d_in, const int* in_sizes, int n_in,
                              void* d_out, int out_size, void* d_ws, size_t ws_size,
                              hipStream_t stream) {
  const float* v   = (const float*)d_in[0];
  const float* Hm  = (const float*)d_in[1];
  const float* y   = (const float*)d_in[2];
  const float* snr = (const float*)d_in[3];
  const float* w1  = (const float*)d_in[4];
  const float* b1  = (const float*)d_in[5];
  const float* w2  = (const float*)d_in[6];
  const float* b2  = (const float*)d_in[7];
  const float* w3  = (const float*)d_in[8];
  const float* b3  = (const float*)d_in[9];
  const float* wy  = (const float*)d_in[10];
  const float* by  = (const float*)d_in[11];
  const float* wh  = (const float*)d_in[12];
  const float* bh  = (const float*)d_in[13];
  const float* wd  = (const float*)d_in[14];
  const float* bd  = (const float*)d_in[15];
  const float* sy  = (const float*)d_in[16];
  const float* sH  = (const float*)d_in[17];
  const float* sd  = (const float*)d_in[18];

  float* out = (float*)d_out;

  double* ws_partial = (double*)d_ws;
  double* ws_hpmean  = ws_partial + 32768;
  float*  ws_ss      = (float*)(ws_hpmean + 4096);
  uint32_t* ws_keys  = (uint32_t*)(ws_ss + 18);

  k0_setup<<<1, 64, 0, stream>>>(sy, sH, sd, ws_ss, ws_keys);
  k1a_hpower_partial<<<512, 128, 0, stream>>>(Hm, ws_partial);
  k1b_hpmean<<<16, 256, 0, stream>>>(ws_partial, ws_hpmean);
  k2_main<<<BL, 64, 0, stream>>>(v, Hm, y, snr, w1, b1, w2, b2, w3, b3,
                                 wy, by, wh, bh, wd, bd, ws_hpmean, ws_keys, out);
  kfix<<<BL / 8, 256, 0, stream>>>(v, Hm, y, snr, w1, b1, w2, b2, w3, b3,
                                   wy, by, wh, bh, wd, bd, ws_hpmean, ws_keys, out);
  k3_Hq<<<32768, 256, 0, stream>>>(Hm, ws_ss, out + O_Hbl, out + O_Hq);
  k4_vq<<<4096, 256, 0, stream>>>(v, ws_ss, out + O_dbl, out + O_vq);
  k5_yq<<<512, 256, 0, stream>>>(y, ws_ss, out + O_yba, out + O_yq);
}

// Round 7
// 1140.035 us; speedup vs baseline: 2.3057x; 1.8409x over previous
//
#include <hip/hip_runtime.h>
#include <cstdint>

// ============================================================================
// TripleAdaptiveQuantizerV11 — round 12: half-LDS / half-register MLP k2.
//
// R11 post-mortem: full-unroll held h_in[64]+h_out[64]=128+ live -> compiler
// chose 156 VGPR and spilled ~58 f/lane (WRITE 63MB->308MB, occ 11%). R9
// (rolled jg -> 16KB LDS roundtrip) was spill-free at 92 VGPR but LDS-bound
// at 10 waves/CU. R12: split each 64->64 layer: groups j=0..31 via R9's
// rolled-jg pattern into an 8KB LDS buffer; groups j=32..63 fully unrolled,
// kept in static regs. Peak live ~96+misc (<128) AND LDS=8KB -> per m69's
// buckets: 16 waves/CU (4/SIMD), 1.6x R9. Readback of the LDS half happens
// after h_in dies (DS in-order per wave -> reads precede the next layer's
// overwrites). __launch_bounds__(64,4) pins the 128-VGPR budget.
// Chains stay bias + ascending-i fmaf; lower half passes through f32 LDS
// exactly -> ly/lh/ld bit-identical -> flags / kfix / outputs unchanged.
// Only k2 changed vs R9/R11. Spill tripwire: WRITE_SIZE must be ~63MB.
// ============================================================================

#define JAX_PARTITIONABLE 1

constexpr int BL = 64 * 256;  // 16384 (B*L)

// Output offsets (floats)
constexpr long long O_vq  = 0;
constexpr long long O_Hq  = 2097152;
constexpr long long O_yq  = 18874368;
constexpr long long O_eb  = 19136512;
constexpr long long O_wy  = 20185088;
constexpr long long O_wH  = 20283392;
constexpr long long O_wd  = 26574848;
constexpr long long O_yba = 32866304;
constexpr long long O_Hbl = 32882688;
constexpr long long O_dbl = 33931264;

// flag stash inside the v_q region (k4 overwrites all of v_q afterwards)
constexpr long long F_SAMPLE = 0;        // 1048576 bytes, 1 per (m,k)
constexpr long long F_M      = 1048576;  // 16384 bytes, 1 per m

#define MARGIN_THETA 3e-4

// ---------------------------------------------------------------- threefry
__device__ __forceinline__ uint32_t rotl32(uint32_t v, int d) {
  return (v << d) | (v >> (32 - d));
}

__device__ __forceinline__ void threefry2x32(uint32_t k0, uint32_t k1,
                                             uint32_t x0, uint32_t x1,
                                             uint32_t& o0, uint32_t& o1) {
  const uint32_t ks2 = k0 ^ k1 ^ 0x1BD11BDAu;
  x0 += k0; x1 += k1;
  x0 += x1; x1 = rotl32(x1, 13); x1 ^= x0;
  x0 += x1; x1 = rotl32(x1, 15); x1 ^= x0;
  x0 += x1; x1 = rotl32(x1, 26); x1 ^= x0;
  x0 += x1; x1 = rotl32(x1, 6);  x1 ^= x0;
  x0 += k1; x1 += ks2 + 1u;
  x0 += x1; x1 = rotl32(x1, 17); x1 ^= x0;
  x0 += x1; x1 = rotl32(x1, 29); x1 ^= x0;
  x0 += x1; x1 = rotl32(x1, 16); x1 ^= x0;
  x0 += x1; x1 = rotl32(x1, 24); x1 ^= x0;
  x0 += ks2; x1 += k0 + 2u;
  x0 += x1; x1 = rotl32(x1, 13); x1 ^= x0;
  x0 += x1; x1 = rotl32(x1, 15); x1 ^= x0;
  x0 += x1; x1 = rotl32(x1, 26); x1 ^= x0;
  x0 += x1; x1 = rotl32(x1, 6);  x1 ^= x0;
  x0 += k0; x1 += k1 + 3u;
  x0 += x1; x1 = rotl32(x1, 17); x1 ^= x0;
  x0 += x1; x1 = rotl32(x1, 29); x1 ^= x0;
  x0 += x1; x1 = rotl32(x1, 16); x1 ^= x0;
  x0 += x1; x1 = rotl32(x1, 24); x1 ^= x0;
  x0 += k1; x1 += ks2 + 4u;
  x0 += x1; x1 = rotl32(x1, 13); x1 ^= x0;
  x0 += x1; x1 = rotl32(x1, 15); x1 ^= x0;
  x0 += x1; x1 = rotl32(x1, 26); x1 ^= x0;
  x0 += x1; x1 = rotl32(x1, 6);  x1 ^= x0;
  x0 += ks2; x1 += k0 + 5u;
  o0 = x0; o1 = x1;
}

__device__ __forceinline__ uint32_t jax_randbits(uint32_t k0, uint32_t k1,
                                                 uint32_t e, uint32_t size) {
#if JAX_PARTITIONABLE
  (void)size;
  uint32_t o0, o1;
  threefry2x32(k0, k1, 0u, e, o0, o1);
  return o0 ^ o1;
#else
  const uint32_t half = size >> 1;
  uint32_t o0, o1;
  if (e < half) { threefry2x32(k0, k1, e, e + half, o0, o1); return o0; }
  threefry2x32(k0, k1, e - half, e, o0, o1); return o1;
#endif
}

// exact f32 replication of jax.random.uniform(minval=1e-10, maxval=1.0)
__device__ __forceinline__ float bits_to_unif(uint32_t bits) {
  float f = __uint_as_float((bits >> 9) | 0x3f800000u) - 1.0f;
  return fmaxf(1e-10f, f + 1e-10f);
}

// ---------------------------------------------------------------- helpers
__device__ __forceinline__ double wave_sum_f64(double x) {
#pragma unroll
  for (int off = 32; off > 0; off >>= 1) x += __shfl_xor(x, off);
  return x;
}

__device__ __forceinline__ void argmax_gap6(const double* s, int& arg, double& gap) {
  int a = 0;
#pragma unroll
  for (int j = 1; j < 6; ++j) if (s[j] > s[a]) a = j;
  double second = -1e300;
#pragma unroll
  for (int j = 0; j < 6; ++j) if (j != a && s[j] > second) second = s[j];
  arg = a; gap = s[a] - second;
}

__device__ __forceinline__ float idx_to_bits(int i) {
  return (float)((i < 4) ? 2 * (i + 1) : (i == 4 ? 12 : 16));
}

// ---------------------------------------------------------------- K0: ss + keys
__global__ void k0_setup(const float* __restrict__ sy, const float* __restrict__ sH,
                         const float* __restrict__ sd, float* __restrict__ ss,
                         uint32_t* __restrict__ keys) {
  const int t = threadIdx.x;
  if (t < 18) {
    const int tensor = t / 6, i = t % 6;
    const int qp_[6] = {1, 7, 31, 127, 2047, 32767};
    const long long sizes[3] = {262144LL, 16777216LL, 2097152LL};  // y, H, v
    const float* sarr = tensor == 0 ? sy : (tensor == 1 ? sH : sd);
    const double g64 = 1.0 / sqrt((double)(sizes[tensor] * (long long)qp_[i]));
    const float g32 = (float)g64;
    const float s = sarr[i];
    const float t1 = s * g32;
    ss[t] = t1 + (s - t1);  // _grad_scale forward, exact f32 sequence
  }
#if JAX_PARTITIONABLE
  if (t >= 32 && t < 35) {
    uint32_t o0, o1;
    threefry2x32(0u, 42u, 0u, (uint32_t)(t - 32), o0, o1);
    keys[(t - 32) * 2 + 0] = o0;
    keys[(t - 32) * 2 + 1] = o1;
  }
#else
  if (t == 32) {
    uint32_t a0, b0, a1, b1, a2, b2;
    threefry2x32(0u, 42u, 0u, 3u, a0, b0);
    threefry2x32(0u, 42u, 1u, 4u, a1, b1);
    threefry2x32(0u, 42u, 2u, 5u, a2, b2);
    keys[0] = a0; keys[1] = a1;
    keys[2] = a2; keys[3] = b0;
    keys[4] = b1; keys[5] = b2;
  }
#endif
}

// ---------------------------------------------------------------- K1: hp_mean
__global__ __launch_bounds__(128) void k1a_hpower_partial(
    const float* __restrict__ Hm, double* __restrict__ partial) {
  const int blk = blockIdx.x;       // 512 = 64 b * 8 l-chunks
  const int b = blk >> 3, lc = blk & 7;
  const int t = threadIdx.x;        // 128 = (k,c)
  const float* base = Hm + (size_t)(b * 256 + lc * 32) * 1024;
  double acc = 0.0;
  for (int l = 0; l < 32; ++l) {
#pragma unroll
    for (int n = 0; n < 8; ++n) {
      const float x = base[(size_t)l * 1024 + n * 128 + t];
      acc = fma((double)x, (double)x, acc);
    }
  }
  const double other = __shfl_xor(acc, 1);
  if ((t & 1) == 0) partial[(size_t)blk * 64 + (t >> 1)] = acc + other;
}

__global__ void k1b_hpmean(const double* __restrict__ partial,
                           double* __restrict__ hp_mean) {
  const int id = blockIdx.x * blockDim.x + threadIdx.x;  // 4096 = b*64+k
  if (id >= 4096) return;
  const int b = id >> 6, k = id & 63;
  double s = 0.0;
#pragma unroll
  for (int lc = 0; lc < 8; ++lc) s += partial[(size_t)(b * 8 + lc) * 64 + k];
  hp_mean[id] = s * (1.0 / 256.0);
}

// ---------------------------------------------------------------- layer 64->64
// Half-split: outputs j=0..31 via rolled-jg -> 8KB LDS (R9's proven 92-VGPR
// pattern); outputs j=32..63 fully unrolled, kept in static regs (hi).
// Lower half read back AFTER the caller's hin is dead (peak live ~96).
// Chain per output: a = B[j]; fmaf(W[j*64+i], x, a) ascending i — identical
// numerics to R9/R11; lower half passes through f32 LDS exactly.
__device__ __forceinline__ void layer64_split(const float (&hin)[64],
                                              const float* __restrict__ W,
                                              const float* __restrict__ B,
                                              float* __restrict__ buf, int lane,
                                              float (&lo)[32], float (&hi)[32]) {
  // groups 0..3 (j = 0..31): rolled jg, results -> LDS slots 0..31
#pragma unroll 1
  for (int jg = 0; jg < 4; ++jg) {
    float a[8];
#pragma unroll
    for (int q = 0; q < 8; ++q) a[q] = B[jg * 8 + q];
#pragma unroll
    for (int i = 0; i < 64; ++i) {
      const float x = hin[i];
#pragma unroll
      for (int q = 0; q < 8; ++q)
        a[q] = fmaf(W[(jg * 8 + q) * 64 + i], x, a[q]);
    }
#pragma unroll
    for (int q = 0; q < 8; ++q)
      buf[(jg * 8 + q) * 64 + lane] = fmaxf(a[q], 0.0f);
  }
  // groups 4..7 (j = 32..63): fully unrolled, static regs
#pragma unroll
  for (int jg = 4; jg < 8; ++jg) {
    float a[8];
#pragma unroll
    for (int q = 0; q < 8; ++q) a[q] = B[jg * 8 + q];
#pragma unroll
    for (int i = 0; i < 64; ++i) {
      const float x = hin[i];
#pragma unroll
      for (int q = 0; q < 8; ++q)
        a[q] = fmaf(W[(jg * 8 + q) * 64 + i], x, a[q]);
    }
#pragma unroll
    for (int q = 0; q < 8; ++q)
      hi[(jg - 4) * 8 + q] = fmaxf(a[q], 0.0f);
  }
  // read back lower half (hin dead now; DS in-order per wave guarantees
  // these reads complete before the next layer's writes to the same slots)
#pragma unroll
  for (int i = 0; i < 32; ++i) lo[i] = buf[i * 64 + lane];
}

// ---------------------------------------------------------------- K2: main
// ONE m per 64-thread (1-wave) block; lane = k. No barriers, 8KB LDS.
// Weights via scalar pipe; activations in VGPRs with half-LDS roundtrip.
__global__ __launch_bounds__(64, 4) void k2_main(
    const float* __restrict__ v, const float* __restrict__ Hm,
    const float* __restrict__ y, const float* __restrict__ snr,
    const float* __restrict__ w1, const float* __restrict__ b1,
    const float* __restrict__ w2, const float* __restrict__ b2,
    const float* __restrict__ w3, const float* __restrict__ b3,
    const float* __restrict__ wy, const float* __restrict__ by,
    const float* __restrict__ wh, const float* __restrict__ bh,
    const float* __restrict__ wd, const float* __restrict__ bd,
    const double* __restrict__ hp_mean, const uint32_t* __restrict__ keys,
    float* __restrict__ out) {
  const int lane = threadIdx.x;
  const int m = blockIdx.x;

  __shared__ __align__(16) float buf[2048];  // 8192 B: [j<32][lane]

  // ---- features (f64 op order identical to R9/R11) ----
  float f[9];
  {
    const float2* Hp = (const float2*)Hm + (size_t)m * 512;
    double aw[4];
#pragma unroll
    for (int w = 0; w < 4; ++w) {
      double acc = 0.0;
#pragma unroll
      for (int nn = 0; nn < 2; ++nn) {
        const float2 h2v = Hp[(2 * w + nn) * 64 + lane];
        acc = fma((double)h2v.x, (double)h2v.x, acc);
        acc = fma((double)h2v.y, (double)h2v.y, acc);
      }
      aw[w] = acc;
    }
    const double hp = ((aw[0] + aw[1]) + aw[2]) + aw[3];
    const double tp = wave_sum_f64(hp);
    double ypart = 0.0;
    if (lane < 16) { const double yv = (double)y[m * 16 + lane]; ypart = yv * yv; }
    const double yp = wave_sum_f64(ypart);
    const float2 vv = ((const float2*)v)[m * 64 + lane];
    const float snrv = snr[m * 64 + lane];
    const double hpm = hp_mean[(m >> 8) * 64 + lane];
    f[0] = (float)vv.x;
    f[1] = (float)vv.y;
    f[2] = snrv;
    f[3] = (float)hp;
    f[4] = (float)hpm;
    f[5] = (float)log1p(hp / ((tp - hp) + 1e-10));
    f[6] = (float)log1p(tp);
    f[7] = (float)log1p(yp);
    f[8] = (float)sqrt(fma((double)vv.x, (double)vv.x,
                           fma((double)vv.y, (double)vv.y, 1e-10)));
  }

  // ---- L1: 9 -> 64, all static indices, registers only ----
  float h1[64];
#pragma unroll
  for (int j = 0; j < 64; ++j) {
    float a = b1[j];
#pragma unroll
    for (int i = 0; i < 9; ++i) a = fmaf(w1[j * 9 + i], f[i], a);
    h1[j] = fmaxf(a, 0.0f);
  }

  // ---- L2: 64 -> 64 half-split ----
  float lo2[32], hi2[32];
  layer64_split(h1, w2, b2, buf, lane, lo2, hi2);
  float h2[64];
#pragma unroll
  for (int i = 0; i < 32; ++i) { h2[i] = lo2[i]; h2[32 + i] = hi2[i]; }

  // ---- L3: 64 -> 64 half-split ----
  float lo3[32], hi3[32];
  layer64_split(h2, w3, b3, buf, lane, lo3, hi3);
  float h3[64];
#pragma unroll
  for (int i = 0; i < 32; ++i) { h3[i] = lo3[i]; h3[32 + i] = hi3[i]; }

  // ---- heads: 64 -> 6+6+6, registers (same chains as R9/R11) ----
  float ly[6], lh[6], ld[6];
#pragma unroll
  for (int r = 0; r < 6; ++r) {
    float a = by[r];
#pragma unroll
    for (int i = 0; i < 64; ++i) a = fmaf(h3[i], wy[r * 64 + i], a);
    ly[r] = a;
  }
#pragma unroll
  for (int r = 0; r < 6; ++r) {
    float a = bh[r];
#pragma unroll
    for (int i = 0; i < 64; ++i) a = fmaf(h3[i], wh[r * 64 + i], a);
    lh[r] = a;
  }
#pragma unroll
  for (int r = 0; r < 6; ++r) {
    float a = bd[r];
#pragma unroll
    for (int i = 0; i < 64; ++i) a = fmaf(h3[i], wd[r * 64 + i], a);
    ld[r] = a;
  }

  // ---- phase C: selection (verbatim R9/R11), lane = k ----
  const int k = lane;

  const uint32_t g1k0 = keys[0], g1k1 = keys[1];
  const uint32_t g2k0 = keys[2], g2k1 = keys[3];
  const uint32_t g3k0 = keys[4], g3k1 = keys[5];

  double sH[6], sD[6];
  const uint32_t eH = (uint32_t)(m * 64 + k) * 6u;
#pragma unroll
  for (int j = 0; j < 6; ++j) {
    const float u = bits_to_unif(jax_randbits(g2k0, g2k1, eH + j, 6291456u));
    sH[j] = (double)lh[j] + (double)(-logf(-logf(u)));
  }
#pragma unroll
  for (int j = 0; j < 6; ++j) {
    const float u = bits_to_unif(jax_randbits(g3k0, g3k1, eH + j, 6291456u));
    sD[j] = (double)ld[j] + (double)(-logf(-logf(u)));
  }
  int argH, argD; double gapH, gapD;
  argmax_gap6(sH, argH, gapH);
  argmax_gap6(sD, argD, gapD);

  double lysum[6];
#pragma unroll
  for (int j = 0; j < 6; ++j) lysum[j] = wave_sum_f64((double)ly[j]);

  int argY = 0; double gapY = 1e30;
  if (k == 0) {
    double sY[6];
#pragma unroll
    for (int j = 0; j < 6; ++j) {
      const float u = bits_to_unif(jax_randbits(g1k0, g1k1, (uint32_t)(m * 6 + j), 98304u));
      sY[j] = lysum[j] * (1.0 / 64.0) - log(-log((double)u));
    }
    argmax_gap6(sY, argY, gapY);
  }
  const int needY = __shfl((k == 0 && gapY < MARGIN_THETA) ? 1 : 0, 0);
  const bool fH = gapH < MARGIN_THETA;
  const bool fD = gapD < MARGIN_THETA;

  uint8_t* flags = (uint8_t*)(out + O_vq);
  flags[F_SAMPLE + (size_t)m * 64 + k] = (uint8_t)((fH ? 1 : 0) | (fD ? 2 : 0));
  const bool anyHD = __ballot(fH || fD) != 0ull;
  if (k == 0)
    flags[F_M + m] = (uint8_t)(((anyHD || needY) ? 1 : 0) | (needY ? 2 : 0));

  argY = __shfl(argY, 0);

  const float bY = 16.0f * idx_to_bits(argY);   // 2*N*bits
  const float bH = 16.0f * idx_to_bits(argH);
  const float bD = 2.0f * idx_to_bits(argD);

  if (k == 0) {
    out[O_yba + m] = bY;
#pragma unroll
    for (int j = 0; j < 6; ++j) out[O_wy + m * 6 + j] = (j == argY) ? 1.0f : 0.0f;
  }
  out[O_Hbl + (size_t)m * 64 + k] = bH;
  out[O_dbl + (size_t)m * 64 + k] = bD;
  out[O_eb + (size_t)m * 64 + k] = (bY * 0.015625f + bH) + bD;
#pragma unroll
  for (int j = 0; j < 6; ++j) {
    out[O_wH + (size_t)(m * 64 + k) * 6 + j] = (j == argH) ? 1.0f : 0.0f;
    out[O_wd + (size_t)(m * 64 + k) * 6 + j] = (j == argD) ? 1.0f : 0.0f;
  }
}

// ---------------------------------------------------------------- f64 helpers
// f64 variant for kfix: weights f32 in LDS (exact convert), act f64 [i][k].
template <int NI>
__device__ __forceinline__ void gemm64_f64(const double* __restrict__ inT,
                                           const float* __restrict__ WT,
                                           const float* __restrict__ bias,
                                           double* __restrict__ outT, int t) {
  const int k0 = (t & 15) * 4;
  const int j0 = (t >> 4) * 4;
  double acc[16];
#pragma unroll
  for (int jj = 0; jj < 4; ++jj) {
    const double bj = (double)bias[j0 + jj];
#pragma unroll
    for (int kk = 0; kk < 4; ++kk) acc[jj * 4 + kk] = bj;
  }
#pragma unroll 8
  for (int i = 0; i < NI; ++i) {
    const double x0 = inT[i * 68 + k0 + 0];
    const double x1 = inT[i * 68 + k0 + 1];
    const double x2 = inT[i * 68 + k0 + 2];
    const double x3 = inT[i * 68 + k0 + 3];
    const float4 wf = *(const float4*)&WT[i * 64 + j0];
    const double w0 = (double)wf.x, w1 = (double)wf.y;
    const double w2 = (double)wf.z, w3 = (double)wf.w;
    acc[0]  = fma(w0, x0, acc[0]);
    acc[1]  = fma(w0, x1, acc[1]);
    acc[2]  = fma(w0, x2, acc[2]);
    acc[3]  = fma(w0, x3, acc[3]);
    acc[4]  = fma(w1, x0, acc[4]);
    acc[5]  = fma(w1, x1, acc[5]);
    acc[6]  = fma(w1, x2, acc[6]);
    acc[7]  = fma(w1, x3, acc[7]);
    acc[8]  = fma(w2, x0, acc[8]);
    acc[9]  = fma(w2, x1, acc[9]);
    acc[10] = fma(w2, x2, acc[10]);
    acc[11] = fma(w2, x3, acc[11]);
    acc[12] = fma(w3, x0, acc[12]);
    acc[13] = fma(w3, x1, acc[13]);
    acc[14] = fma(w3, x2, acc[14]);
    acc[15] = fma(w3, x3, acc[15]);
  }
#pragma unroll
  for (int jj = 0; jj < 4; ++jj) {
#pragma unroll
    for (int kk = 0; kk < 4; ++kk) {
      const double a = acc[jj * 4 + kk];
      outT[(j0 + jj) * 68 + k0 + kk] = a > 0.0 ? a : 0.0;  // same relu as ref
    }
  }
}

__device__ __forceinline__ void heads20_f64(const double* __restrict__ actT,
                                            const float* __restrict__ whT,
                                            const float* __restrict__ by,
                                            const float* __restrict__ bh,
                                            const float* __restrict__ bd,
                                            double* __restrict__ headP, int t) {
  const int k = t & 63, w = t >> 6;
  double acc[5];
#pragma unroll
  for (int q = 0; q < 5; ++q) {
    const int r = w + 4 * q;
    acc[q] = (r < 6) ? (double)by[r]
           : (r < 12) ? (double)bh[r - 6]
           : (r < 18) ? (double)bd[r - 12] : 0.0;
  }
#pragma unroll 8
  for (int i = 0; i < 64; ++i) {
    const double x = actT[i * 68 + k];
#pragma unroll
    for (int q = 0; q < 5; ++q)
      acc[q] = fma(x, (double)whT[(w + 4 * q) * 64 + i], acc[q]);
  }
#pragma unroll
  for (int q = 0; q < 5; ++q) {
    const int r = w + 4 * q;
    if (r < 18) headP[k * 20 + r] = acc[q];
  }
}

// ---------------------------------------------------------------- kfix
// 256-thread block handles 8 m's; per flagged m runs the f64 LDS-gemm MLP.
__global__ __launch_bounds__(256, 1) void kfix(
    const float* __restrict__ v, const float* __restrict__ Hm,
    const float* __restrict__ y, const float* __restrict__ snr,
    const float* __restrict__ w1, const float* __restrict__ b1,
    const float* __restrict__ w2, const float* __restrict__ b2,
    const float* __restrict__ w3, const float* __restrict__ b3,
    const float* __restrict__ wy, const float* __restrict__ by,
    const float* __restrict__ wh, const float* __restrict__ bh,
    const float* __restrict__ wd, const float* __restrict__ bd,
    const double* __restrict__ hp_mean, const uint32_t* __restrict__ keys,
    float* __restrict__ out) {
  const int t = threadIdx.x;
  const int lane = t & 63;
  const int wvx = t >> 6;
  const int m0 = blockIdx.x * 8;
  const uint8_t* flags = (const uint8_t*)(out + O_vq);

  __shared__ uint32_t mfs[8];
  __shared__ __align__(32) char smem[120064];
  float*  w1T     = (float*)smem;                 // 576 f  [i<9][j]
  float*  w2T     = (float*)(smem + 2304);        // 4096 f [i][j]
  float*  w3T     = (float*)(smem + 18688);       // 4096 f [i][j]
  float*  whT     = (float*)(smem + 35072);       // 1280 f [r<20][i]
  double* actA64  = (double*)(smem + 40192);      // 64x68 d [row][k]
  double* actB64  = (double*)(smem + 75008);      // 64x68 d
  double* headP64 = (double*)(smem + 109824);     // 64x20 d [k][20]
  double* hp4     = actB64;                       // alias (pre-L1 only)

  if (t < 8) mfs[t] = flags[F_M + m0 + t];
  __syncthreads();
  bool any = false;
#pragma unroll
  for (int i = 0; i < 8; ++i) any |= (mfs[i] != 0);
  if (!any) return;

  // stage weights once (same transposed layouts as R5)
  for (int idx = t; idx < 576; idx += 256) {
    const int i = idx >> 6, j = idx & 63;
    w1T[idx] = w1[j * 9 + i];
  }
  for (int idx = t; idx < 4096; idx += 256) {
    const int i = idx >> 6, j = idx & 63;
    w2T[idx] = w2[j * 64 + i];
    w3T[idx] = w3[j * 64 + i];
  }
  for (int idx = t; idx < 1280; idx += 256) {
    const int r = idx >> 6, i = idx & 63;
    whT[idx] = (r < 6) ? wy[r * 64 + i]
             : (r < 12) ? wh[(r - 6) * 64 + i]
             : (r < 18) ? wd[(r - 12) * 64 + i] : 0.0f;
  }

#pragma unroll 1
  for (int mi = 0; mi < 8; ++mi) {
    const uint32_t mf = mfs[mi];
    if (mf == 0) continue;  // block-uniform
    const int m = m0 + mi;

    // hp partials, identical op order to k2
    {
      const float2* Hp = (const float2*)Hm + (size_t)m * 512;
      double acc = 0.0;
#pragma unroll
      for (int nn = 0; nn < 2; ++nn) {
        const float2 h2v = Hp[(2 * wvx + nn) * 64 + lane];
        acc = fma((double)h2v.x, (double)h2v.x, acc);
        acc = fma((double)h2v.y, (double)h2v.y, acc);
      }
      __syncthreads();  // weights staged / prior-m reads done before actB reuse
      hp4[wvx * 64 + lane] = acc;
    }
    __syncthreads();

    // wave 0: f64 features -> actA64 rows 0..8
    if (t < 64) {
      const double hp = ((hp4[lane] + hp4[64 + lane]) + hp4[128 + lane]) + hp4[192 + lane];
      const double tp = wave_sum_f64(hp);
      double ypart = 0.0;
      if (lane < 16) { const double yv = (double)y[m * 16 + lane]; ypart = yv * yv; }
      const double yp = wave_sum_f64(ypart);
      const float2 vv = ((const float2*)v)[m * 64 + lane];
      const float snrv = snr[m * 64 + lane];
      const double hpm = hp_mean[(m >> 8) * 64 + lane];
      double f[9];
      f[0] = (double)vv.x;
      f[1] = (double)vv.y;
      f[2] = (double)snrv;
      f[3] = hp;
      f[4] = hpm;
      f[5] = log1p(hp / ((tp - hp) + 1e-10));
      f[6] = log1p(tp);
      f[7] = log1p(yp);
      f[8] = sqrt(fma((double)vv.x, (double)vv.x,
                      fma((double)vv.y, (double)vv.y, 1e-10)));
#pragma unroll
      for (int i = 0; i < 9; ++i) actA64[i * 68 + lane] = f[i];
    }
    __syncthreads();

    gemm64_f64<9>(actA64, w1T, b1, actB64, t);
    __syncthreads();
    gemm64_f64<64>(actB64, w2T, b2, actA64, t);
    __syncthreads();
    gemm64_f64<64>(actA64, w3T, b3, actB64, t);
    __syncthreads();
    heads20_f64(actB64, whT, by, bh, bd, headP64, t);
    __syncthreads();

    // wave 0: refine flagged selections
    if (t < 64) {
      const int k = lane;
      const uint8_t f = flags[F_SAMPLE + (size_t)m * 64 + k];
      double lyd[6], lhd[6], ldd[6];
#pragma unroll
      for (int j = 0; j < 6; ++j) {
        lyd[j] = headP64[k * 20 + j];
        lhd[j] = headP64[k * 20 + 6 + j];
        ldd[j] = headP64[k * 20 + 12 + j];
      }
      const uint32_t g1k0 = keys[0], g1k1 = keys[1];
      const uint32_t g2k0 = keys[2], g2k1 = keys[3];
      const uint32_t g3k0 = keys[4], g3k1 = keys[5];
      const uint32_t eH = (uint32_t)(m * 64 + k) * 6u;

      float bHf, bDf;
      if (f & 1) {
        double s2[6];
#pragma unroll
        for (int j = 0; j < 6; ++j) {
          const float u = bits_to_unif(jax_randbits(g2k0, g2k1, eH + j, 6291456u));
          s2[j] = lhd[j] - log(-log((double)u));
        }
        int argH; double g; argmax_gap6(s2, argH, g);
        bHf = 16.0f * idx_to_bits(argH);
        out[O_Hbl + (size_t)m * 64 + k] = bHf;
#pragma unroll
        for (int j = 0; j < 6; ++j)
          out[O_wH + (size_t)(m * 64 + k) * 6 + j] = (j == argH) ? 1.0f : 0.0f;
      } else {
        bHf = out[O_Hbl + (size_t)m * 64 + k];
      }
      if (f & 2) {
        double s2[6];
#pragma unroll
        for (int j = 0; j < 6; ++j) {
          const float u = bits_to_unif(jax_randbits(g3k0, g3k1, eH + j, 6291456u));
          s2[j] = ldd[j] - log(-log((double)u));
        }
        int argD; double g; argmax_gap6(s2, argD, g);
        bDf = 2.0f * idx_to_bits(argD);
        out[O_dbl + (size_t)m * 64 + k] = bDf;
#pragma unroll
        for (int j = 0; j < 6; ++j)
          out[O_wd + (size_t)(m * 64 + k) * 6 + j] = (j == argD) ? 1.0f : 0.0f;
      } else {
        bDf = out[O_dbl + (size_t)m * 64 + k];
      }

      float bYf;
      if (mf & 2) {
        double lys2[6];
#pragma unroll
        for (int j = 0; j < 6; ++j) lys2[j] = wave_sum_f64(lyd[j]);
        int argY = 0;
        if (k == 0) {
          double s2[6];
#pragma unroll
          for (int j = 0; j < 6; ++j) {
            const float u = bits_to_unif(jax_randbits(g1k0, g1k1, (uint32_t)(m * 6 + j), 98304u));
            s2[j] = lys2[j] * (1.0 / 64.0) - log(-log((double)u));
          }
          double g; argmax_gap6(s2, argY, g);
        }
        argY = __shfl(argY, 0);
        bYf = 16.0f * idx_to_bits(argY);
        if (k == 0) {
          out[O_yba + m] = bYf;
#pragma unroll
          for (int j = 0; j < 6; ++j) out[O_wy + m * 6 + j] = (j == argY) ? 1.0f : 0.0f;
        }
      } else {
        bYf = out[O_yba + m];
      }

      out[O_eb + (size_t)m * 64 + k] = (bYf * 0.015625f + bHf) + bDf;
    }
    __syncthreads();  // headP64/actB64 safe before next mi reuses them
  }
}

// ---------------------------------------------------------------- LSQ quant
__device__ __forceinline__ int bits_to_idx(int bits) {
  return (bits <= 8) ? ((bits >> 1) - 1) : ((bits == 12) ? 4 : 5);
}

__device__ __forceinline__ float lsq1(float x, float ssv, float qn, float qp) {
  float t = x / ssv;
  t = fminf(fmaxf(t, qn), qp);
  return rintf(t) * ssv;
}

__global__ void k3_Hq(const float* __restrict__ Hm, const float* __restrict__ ss,
                      const float* __restrict__ Hbits, float* __restrict__ outHq) {
  const int id = blockIdx.x * blockDim.x + threadIdx.x;
  if (id >= 8388608) return;
  const int k = id & 63;
  const int m = id >> 9;
  const int bits = (int)Hbits[(size_t)m * 64 + k] >> 4;
  const int i = bits_to_idx(bits);
  const float ssv = ss[6 + i];
  const float qp = (float)((1 << (bits - 1)) - 1);
  const float qn = -(float)(1 << (bits - 1));
  const float2 x = ((const float2*)Hm)[id];
  float2 o;
  o.x = lsq1(x.x, ssv, qn, qp);
  o.y = lsq1(x.y, ssv, qn, qp);
  ((float2*)outHq)[id] = o;
}

__global__ void k4_vq(const float* __restrict__ v, const float* __restrict__ ss,
                      const float* __restrict__ dbits, float* __restrict__ outvq) {
  const int id = blockIdx.x * blockDim.x + threadIdx.x;
  if (id >= 1048576) return;
  const int bits = (int)dbits[id] >> 1;
  const int i = bits_to_idx(bits);
  const float ssv = ss[12 + i];
  const float qp = (float)((1 << (bits - 1)) - 1);
  const float qn = -(float)(1 << (bits - 1));
  const float2 x = ((const float2*)v)[id];
  float2 o;
  o.x = lsq1(x.x, ssv, qn, qp);
  o.y = lsq1(x.y, ssv, qn, qp);
  ((float2*)outvq)[id] = o;
}

__global__ void k5_yq(const float* __restrict__ y, const float* __restrict__ ss,
                      const float* __restrict__ ybits, float* __restrict__ outyq) {
  const int id = blockIdx.x * blockDim.x + threadIdx.x;
  if (id >= 131072) return;
  const int m = id >> 3;
  const int bits = (int)ybits[m] >> 4;
  const int i = bits_to_idx(bits);
  const float ssv = ss[i];
  const float qp = (float)((1 << (bits - 1)) - 1);
  const float qn = -(float)(1 << (bits - 1));
  const float2 x = ((const float2*)y)[id];
  float2 o;
  o.x = lsq1(x.x, ssv, qn, qp);
  o.y = lsq1(x.y, ssv, qn, qp);
  ((float2*)outyq)[id] = o;
}

// ---------------------------------------------------------------- launch
extern "C" void kernel_launch(void* const* d_in, const int* in_sizes, int n_in,
                              void* d_out, int out_size, void* d_ws, size_t ws_size,
                              hipStream_t stream) {
  const float* v   = (const float*)d_in[0];
  const float* Hm  = (const float*)d_in[1];
  const float* y   = (const float*)d_in[2];
  const float* snr = (const float*)d_in[3];
  const float* w1  = (const float*)d_in[4];
  const float* b1  = (const float*)d_in[5];
  const float* w2  = (const float*)d_in[6];
  const float* b2  = (const float*)d_in[7];
  const float* w3  = (const float*)d_in[8];
  const float* b3  = (const float*)d_in[9];
  const float* wy  = (const float*)d_in[10];
  const float* by  = (const float*)d_in[11];
  const float* wh  = (const float*)d_in[12];
  const float* bh  = (const float*)d_in[13];
  const float* wd  = (const float*)d_in[14];
  const float* bd  = (const float*)d_in[15];
  const float* sy  = (const float*)d_in[16];
  const float* sH  = (const float*)d_in[17];
  const float* sd  = (const float*)d_in[18];

  float* out = (float*)d_out;

  double* ws_partial = (double*)d_ws;
  double* ws_hpmean  = ws_partial + 32768;
  float*  ws_ss      = (float*)(ws_hpmean + 4096);
  uint32_t* ws_keys  = (uint32_t*)(ws_ss + 18);

  k0_setup<<<1, 64, 0, stream>>>(sy, sH, sd, ws_ss, ws_keys);
  k1a_hpower_partial<<<512, 128, 0, stream>>>(Hm, ws_partial);
  k1b_hpmean<<<16, 256, 0, stream>>>(ws_partial, ws_hpmean);
  k2_main<<<BL, 64, 0, stream>>>(v, Hm, y, snr, w1, b1, w2, b2, w3, b3,
                                 wy, by, wh, bh, wd, bd, ws_hpmean, ws_keys, out);
  kfix<<<BL / 8, 256, 0, stream>>>(v, Hm, y, snr, w1, b1, w2, b2, w3, b3,
                                   wy, by, wh, bh, wd, bd, ws_hpmean, ws_keys, out);
  k3_Hq<<<32768, 256, 0, stream>>>(Hm, ws_ss, out + O_Hbl, out + O_Hq);
  k4_vq<<<4096, 256, 0, stream>>>(v, ws_ss, out + O_dbl, out + O_vq);
  k5_yq<<<512, 256, 0, stream>>>(y, ws_ss, out + O_yba, out + O_yq);
}

// Round 8
// 823.249 us; speedup vs baseline: 3.1930x; 1.3848x over previous
//
#include <hip/hip_runtime.h>
#include <cstdint>

// ============================================================================
// TripleAdaptiveQuantizerV12 — round 13: half-LDS MLP k2, unconstrained alloc.
//
// R12 post-mortem: structure right (LDS 8KB, occ 43%, conflicts 0) but
// __launch_bounds__(64,4) made the allocator clamp VGPR=64 (it targets max
// occupancy once a waves-per-eu attr exists) -> ~630MB scratch spill, 835us.
// Empirical law R9-R12: plain __launch_bounds__(64) allocates cleanly (R9:
// 92 VGPR, no spill); any forced cap or >128 live set spills. R13: keep the
// 8KB split but (a) plain __launch_bounds__(64); (b) both layer halves stay
// ROLLED: pass1 j=0..31 -> 8KB LDS; read back lo[32] EARLY (hin live, peak
// 64+32+8~104); pass2 j=32..63 -> same slots (DS in-order per wave: lo reads
// precede pass2 writes); read back hi after hin dies. ~110-125 VGPR ->
// 4 waves/SIMD (VGPR bucket 65-128), LDS allows 20 blocks/CU. 1.6x R9 waves
// with fewer LDS ops/m. Chains bias + ascending-i fmaf; all values pass
// through f32 LDS/regs exactly -> ly/lh/ld bit-identical -> flags / kfix /
// outputs unchanged. Only k2 changed vs R12.
// Tripwires: VGPR>128 -> occ 2/SIMD (~600us); WRITE>>63MB -> spilled.
// ============================================================================

#define JAX_PARTITIONABLE 1

constexpr int BL = 64 * 256;  // 16384 (B*L)

// Output offsets (floats)
constexpr long long O_vq  = 0;
constexpr long long O_Hq  = 2097152;
constexpr long long O_yq  = 18874368;
constexpr long long O_eb  = 19136512;
constexpr long long O_wy  = 20185088;
constexpr long long O_wH  = 20283392;
constexpr long long O_wd  = 26574848;
constexpr long long O_yba = 32866304;
constexpr long long O_Hbl = 32882688;
constexpr long long O_dbl = 33931264;

// flag stash inside the v_q region (k4 overwrites all of v_q afterwards)
constexpr long long F_SAMPLE = 0;        // 1048576 bytes, 1 per (m,k)
constexpr long long F_M      = 1048576;  // 16384 bytes, 1 per m

#define MARGIN_THETA 3e-4

// ---------------------------------------------------------------- threefry
__device__ __forceinline__ uint32_t rotl32(uint32_t v, int d) {
  return (v << d) | (v >> (32 - d));
}

__device__ __forceinline__ void threefry2x32(uint32_t k0, uint32_t k1,
                                             uint32_t x0, uint32_t x1,
                                             uint32_t& o0, uint32_t& o1) {
  const uint32_t ks2 = k0 ^ k1 ^ 0x1BD11BDAu;
  x0 += k0; x1 += k1;
  x0 += x1; x1 = rotl32(x1, 13); x1 ^= x0;
  x0 += x1; x1 = rotl32(x1, 15); x1 ^= x0;
  x0 += x1; x1 = rotl32(x1, 26); x1 ^= x0;
  x0 += x1; x1 = rotl32(x1, 6);  x1 ^= x0;
  x0 += k1; x1 += ks2 + 1u;
  x0 += x1; x1 = rotl32(x1, 17); x1 ^= x0;
  x0 += x1; x1 = rotl32(x1, 29); x1 ^= x0;
  x0 += x1; x1 = rotl32(x1, 16); x1 ^= x0;
  x0 += x1; x1 = rotl32(x1, 24); x1 ^= x0;
  x0 += ks2; x1 += k0 + 2u;
  x0 += x1; x1 = rotl32(x1, 13); x1 ^= x0;
  x0 += x1; x1 = rotl32(x1, 15); x1 ^= x0;
  x0 += x1; x1 = rotl32(x1, 26); x1 ^= x0;
  x0 += x1; x1 = rotl32(x1, 6);  x1 ^= x0;
  x0 += k0; x1 += k1 + 3u;
  x0 += x1; x1 = rotl32(x1, 17); x1 ^= x0;
  x0 += x1; x1 = rotl32(x1, 29); x1 ^= x0;
  x0 += x1; x1 = rotl32(x1, 16); x1 ^= x0;
  x0 += x1; x1 = rotl32(x1, 24); x1 ^= x0;
  x0 += k1; x1 += ks2 + 4u;
  x0 += x1; x1 = rotl32(x1, 13); x1 ^= x0;
  x0 += x1; x1 = rotl32(x1, 15); x1 ^= x0;
  x0 += x1; x1 = rotl32(x1, 26); x1 ^= x0;
  x0 += x1; x1 = rotl32(x1, 6);  x1 ^= x0;
  x0 += ks2; x1 += k0 + 5u;
  o0 = x0; o1 = x1;
}

__device__ __forceinline__ uint32_t jax_randbits(uint32_t k0, uint32_t k1,
                                                 uint32_t e, uint32_t size) {
#if JAX_PARTITIONABLE
  (void)size;
  uint32_t o0, o1;
  threefry2x32(k0, k1, 0u, e, o0, o1);
  return o0 ^ o1;
#else
  const uint32_t half = size >> 1;
  uint32_t o0, o1;
  if (e < half) { threefry2x32(k0, k1, e, e + half, o0, o1); return o0; }
  threefry2x32(k0, k1, e - half, e, o0, o1); return o1;
#endif
}

// exact f32 replication of jax.random.uniform(minval=1e-10, maxval=1.0)
__device__ __forceinline__ float bits_to_unif(uint32_t bits) {
  float f = __uint_as_float((bits >> 9) | 0x3f800000u) - 1.0f;
  return fmaxf(1e-10f, f + 1e-10f);
}

// ---------------------------------------------------------------- helpers
__device__ __forceinline__ double wave_sum_f64(double x) {
#pragma unroll
  for (int off = 32; off > 0; off >>= 1) x += __shfl_xor(x, off);
  return x;
}

__device__ __forceinline__ void argmax_gap6(const double* s, int& arg, double& gap) {
  int a = 0;
#pragma unroll
  for (int j = 1; j < 6; ++j) if (s[j] > s[a]) a = j;
  double second = -1e300;
#pragma unroll
  for (int j = 0; j < 6; ++j) if (j != a && s[j] > second) second = s[j];
  arg = a; gap = s[a] - second;
}

__device__ __forceinline__ float idx_to_bits(int i) {
  return (float)((i < 4) ? 2 * (i + 1) : (i == 4 ? 12 : 16));
}

// ---------------------------------------------------------------- K0: ss + keys
__global__ void k0_setup(const float* __restrict__ sy, const float* __restrict__ sH,
                         const float* __restrict__ sd, float* __restrict__ ss,
                         uint32_t* __restrict__ keys) {
  const int t = threadIdx.x;
  if (t < 18) {
    const int tensor = t / 6, i = t % 6;
    const int qp_[6] = {1, 7, 31, 127, 2047, 32767};
    const long long sizes[3] = {262144LL, 16777216LL, 2097152LL};  // y, H, v
    const float* sarr = tensor == 0 ? sy : (tensor == 1 ? sH : sd);
    const double g64 = 1.0 / sqrt((double)(sizes[tensor] * (long long)qp_[i]));
    const float g32 = (float)g64;
    const float s = sarr[i];
    const float t1 = s * g32;
    ss[t] = t1 + (s - t1);  // _grad_scale forward, exact f32 sequence
  }
#if JAX_PARTITIONABLE
  if (t >= 32 && t < 35) {
    uint32_t o0, o1;
    threefry2x32(0u, 42u, 0u, (uint32_t)(t - 32), o0, o1);
    keys[(t - 32) * 2 + 0] = o0;
    keys[(t - 32) * 2 + 1] = o1;
  }
#else
  if (t == 32) {
    uint32_t a0, b0, a1, b1, a2, b2;
    threefry2x32(0u, 42u, 0u, 3u, a0, b0);
    threefry2x32(0u, 42u, 1u, 4u, a1, b1);
    threefry2x32(0u, 42u, 2u, 5u, a2, b2);
    keys[0] = a0; keys[1] = a1;
    keys[2] = a2; keys[3] = b0;
    keys[4] = b1; keys[5] = b2;
  }
#endif
}

// ---------------------------------------------------------------- K1: hp_mean
__global__ __launch_bounds__(128) void k1a_hpower_partial(
    const float* __restrict__ Hm, double* __restrict__ partial) {
  const int blk = blockIdx.x;       // 512 = 64 b * 8 l-chunks
  const int b = blk >> 3, lc = blk & 7;
  const int t = threadIdx.x;        // 128 = (k,c)
  const float* base = Hm + (size_t)(b * 256 + lc * 32) * 1024;
  double acc = 0.0;
  for (int l = 0; l < 32; ++l) {
#pragma unroll
    for (int n = 0; n < 8; ++n) {
      const float x = base[(size_t)l * 1024 + n * 128 + t];
      acc = fma((double)x, (double)x, acc);
    }
  }
  const double other = __shfl_xor(acc, 1);
  if ((t & 1) == 0) partial[(size_t)blk * 64 + (t >> 1)] = acc + other;
}

__global__ void k1b_hpmean(const double* __restrict__ partial,
                           double* __restrict__ hp_mean) {
  const int id = blockIdx.x * blockDim.x + threadIdx.x;  // 4096 = b*64+k
  if (id >= 4096) return;
  const int b = id >> 6, k = id & 63;
  double s = 0.0;
#pragma unroll
  for (int lc = 0; lc < 8; ++lc) s += partial[(size_t)(b * 8 + lc) * 64 + k];
  hp_mean[id] = s * (1.0 / 256.0);
}

// ---------------------------------------------------------------- layer 64->64
// 8KB-LDS two-pass layer, both passes rolled (R9's proven jg pattern):
//   pass1: j=0..31 -> buf; readback hout[0..31] EARLY (hin live, peak ~104);
//   pass2: j=32..63 -> same buf slots (DS in-order per wave: the readback
//   reads precede pass2's writes); readback hout[32..63] (hin dead).
// Chain per output: a = B[j]; fmaf(W[j*64+i], x, a) ascending i — identical
// numerics to R9/R12; all values pass through f32 LDS exactly.
__device__ __forceinline__ void layer64_8k(const float (&hin)[64],
                                           const float* __restrict__ W,
                                           const float* __restrict__ B,
                                           float* __restrict__ buf, int lane,
                                           float (&hout)[64]) {
#pragma unroll 1
  for (int jg = 0; jg < 4; ++jg) {
    float a[8];
#pragma unroll
    for (int q = 0; q < 8; ++q) a[q] = B[jg * 8 + q];
#pragma unroll
    for (int i = 0; i < 64; ++i) {
      const float x = hin[i];
#pragma unroll
      for (int q = 0; q < 8; ++q)
        a[q] = fmaf(W[(jg * 8 + q) * 64 + i], x, a[q]);
    }
#pragma unroll
    for (int q = 0; q < 8; ++q)
      buf[(jg * 8 + q) * 64 + lane] = fmaxf(a[q], 0.0f);
  }
  // early readback of lower half (hin still live; same-wave DS ordering
  // guarantees these reads complete before pass2 overwrites the slots)
#pragma unroll
  for (int i = 0; i < 32; ++i) hout[i] = buf[i * 64 + lane];
#pragma unroll 1
  for (int jg = 0; jg < 4; ++jg) {
    float a[8];
#pragma unroll
    for (int q = 0; q < 8; ++q) a[q] = B[32 + jg * 8 + q];
#pragma unroll
    for (int i = 0; i < 64; ++i) {
      const float x = hin[i];
#pragma unroll
      for (int q = 0; q < 8; ++q)
        a[q] = fmaf(W[(32 + jg * 8 + q) * 64 + i], x, a[q]);
    }
#pragma unroll
    for (int q = 0; q < 8; ++q)
      buf[(jg * 8 + q) * 64 + lane] = fmaxf(a[q], 0.0f);
  }
#pragma unroll
  for (int i = 0; i < 32; ++i) hout[32 + i] = buf[i * 64 + lane];
}

// ---------------------------------------------------------------- K2: main
// ONE m per 64-thread (1-wave) block; lane = k. No barriers, 8KB LDS.
// Weights via scalar pipe; activations in VGPRs with 8KB-LDS roundtrip.
__global__ __launch_bounds__(64) void k2_main(
    const float* __restrict__ v, const float* __restrict__ Hm,
    const float* __restrict__ y, const float* __restrict__ snr,
    const float* __restrict__ w1, const float* __restrict__ b1,
    const float* __restrict__ w2, const float* __restrict__ b2,
    const float* __restrict__ w3, const float* __restrict__ b3,
    const float* __restrict__ wy, const float* __restrict__ by,
    const float* __restrict__ wh, const float* __restrict__ bh,
    const float* __restrict__ wd, const float* __restrict__ bd,
    const double* __restrict__ hp_mean, const uint32_t* __restrict__ keys,
    float* __restrict__ out) {
  const int lane = threadIdx.x;
  const int m = blockIdx.x;

  __shared__ __align__(16) float buf[2048];  // 8192 B: [j<32][lane]

  // ---- features (f64 op order identical to R9/R12) ----
  float f[9];
  {
    const float2* Hp = (const float2*)Hm + (size_t)m * 512;
    double aw[4];
#pragma unroll
    for (int w = 0; w < 4; ++w) {
      double acc = 0.0;
#pragma unroll
      for (int nn = 0; nn < 2; ++nn) {
        const float2 h2v = Hp[(2 * w + nn) * 64 + lane];
        acc = fma((double)h2v.x, (double)h2v.x, acc);
        acc = fma((double)h2v.y, (double)h2v.y, acc);
      }
      aw[w] = acc;
    }
    const double hp = ((aw[0] + aw[1]) + aw[2]) + aw[3];
    const double tp = wave_sum_f64(hp);
    double ypart = 0.0;
    if (lane < 16) { const double yv = (double)y[m * 16 + lane]; ypart = yv * yv; }
    const double yp = wave_sum_f64(ypart);
    const float2 vv = ((const float2*)v)[m * 64 + lane];
    const float snrv = snr[m * 64 + lane];
    const double hpm = hp_mean[(m >> 8) * 64 + lane];
    f[0] = (float)vv.x;
    f[1] = (float)vv.y;
    f[2] = snrv;
    f[3] = (float)hp;
    f[4] = (float)hpm;
    f[5] = (float)log1p(hp / ((tp - hp) + 1e-10));
    f[6] = (float)log1p(tp);
    f[7] = (float)log1p(yp);
    f[8] = (float)sqrt(fma((double)vv.x, (double)vv.x,
                           fma((double)vv.y, (double)vv.y, 1e-10)));
  }

  // ---- L1: 9 -> 64, all static indices, registers only ----
  float h1[64];
#pragma unroll
  for (int j = 0; j < 64; ++j) {
    float a = b1[j];
#pragma unroll
    for (int i = 0; i < 9; ++i) a = fmaf(w1[j * 9 + i], f[i], a);
    h1[j] = fmaxf(a, 0.0f);
  }

  // ---- L2 / L3: 64 -> 64 via 8KB two-pass ----
  float h2[64];
  layer64_8k(h1, w2, b2, buf, lane, h2);
  float h3[64];
  layer64_8k(h2, w3, b3, buf, lane, h3);

  // ---- heads: 64 -> 6+6+6, registers (same chains as R9/R12) ----
  float ly[6], lh[6], ld[6];
#pragma unroll
  for (int r = 0; r < 6; ++r) {
    float a = by[r];
#pragma unroll
    for (int i = 0; i < 64; ++i) a = fmaf(h3[i], wy[r * 64 + i], a);
    ly[r] = a;
  }
#pragma unroll
  for (int r = 0; r < 6; ++r) {
    float a = bh[r];
#pragma unroll
    for (int i = 0; i < 64; ++i) a = fmaf(h3[i], wh[r * 64 + i], a);
    lh[r] = a;
  }
#pragma unroll
  for (int r = 0; r < 6; ++r) {
    float a = bd[r];
#pragma unroll
    for (int i = 0; i < 64; ++i) a = fmaf(h3[i], wd[r * 64 + i], a);
    ld[r] = a;
  }

  // ---- phase C: selection (verbatim R9/R12), lane = k ----
  const int k = lane;

  const uint32_t g1k0 = keys[0], g1k1 = keys[1];
  const uint32_t g2k0 = keys[2], g2k1 = keys[3];
  const uint32_t g3k0 = keys[4], g3k1 = keys[5];

  double sH[6], sD[6];
  const uint32_t eH = (uint32_t)(m * 64 + k) * 6u;
#pragma unroll
  for (int j = 0; j < 6; ++j) {
    const float u = bits_to_unif(jax_randbits(g2k0, g2k1, eH + j, 6291456u));
    sH[j] = (double)lh[j] + (double)(-logf(-logf(u)));
  }
#pragma unroll
  for (int j = 0; j < 6; ++j) {
    const float u = bits_to_unif(jax_randbits(g3k0, g3k1, eH + j, 6291456u));
    sD[j] = (double)ld[j] + (double)(-logf(-logf(u)));
  }
  int argH, argD; double gapH, gapD;
  argmax_gap6(sH, argH, gapH);
  argmax_gap6(sD, argD, gapD);

  double lysum[6];
#pragma unroll
  for (int j = 0; j < 6; ++j) lysum[j] = wave_sum_f64((double)ly[j]);

  int argY = 0; double gapY = 1e30;
  if (k == 0) {
    double sY[6];
#pragma unroll
    for (int j = 0; j < 6; ++j) {
      const float u = bits_to_unif(jax_randbits(g1k0, g1k1, (uint32_t)(m * 6 + j), 98304u));
      sY[j] = lysum[j] * (1.0 / 64.0) - log(-log((double)u));
    }
    argmax_gap6(sY, argY, gapY);
  }
  const int needY = __shfl((k == 0 && gapY < MARGIN_THETA) ? 1 : 0, 0);
  const bool fH = gapH < MARGIN_THETA;
  const bool fD = gapD < MARGIN_THETA;

  uint8_t* flags = (uint8_t*)(out + O_vq);
  flags[F_SAMPLE + (size_t)m * 64 + k] = (uint8_t)((fH ? 1 : 0) | (fD ? 2 : 0));
  const bool anyHD = __ballot(fH || fD) != 0ull;
  if (k == 0)
    flags[F_M + m] = (uint8_t)(((anyHD || needY) ? 1 : 0) | (needY ? 2 : 0));

  argY = __shfl(argY, 0);

  const float bY = 16.0f * idx_to_bits(argY);   // 2*N*bits
  const float bH = 16.0f * idx_to_bits(argH);
  const float bD = 2.0f * idx_to_bits(argD);

  if (k == 0) {
    out[O_yba + m] = bY;
#pragma unroll
    for (int j = 0; j < 6; ++j) out[O_wy + m * 6 + j] = (j == argY) ? 1.0f : 0.0f;
  }
  out[O_Hbl + (size_t)m * 64 + k] = bH;
  out[O_dbl + (size_t)m * 64 + k] = bD;
  out[O_eb + (size_t)m * 64 + k] = (bY * 0.015625f + bH) + bD;
#pragma unroll
  for (int j = 0; j < 6; ++j) {
    out[O_wH + (size_t)(m * 64 + k) * 6 + j] = (j == argH) ? 1.0f : 0.0f;
    out[O_wd + (size_t)(m * 64 + k) * 6 + j] = (j == argD) ? 1.0f : 0.0f;
  }
}

// ---------------------------------------------------------------- f64 helpers
// f64 variant for kfix: weights f32 in LDS (exact convert), act f64 [i][k].
template <int NI>
__device__ __forceinline__ void gemm64_f64(const double* __restrict__ inT,
                                           const float* __restrict__ WT,
                                           const float* __restrict__ bias,
                                           double* __restrict__ outT, int t) {
  const int k0 = (t & 15) * 4;
  const int j0 = (t >> 4) * 4;
  double acc[16];
#pragma unroll
  for (int jj = 0; jj < 4; ++jj) {
    const double bj = (double)bias[j0 + jj];
#pragma unroll
    for (int kk = 0; kk < 4; ++kk) acc[jj * 4 + kk] = bj;
  }
#pragma unroll 8
  for (int i = 0; i < NI; ++i) {
    const double x0 = inT[i * 68 + k0 + 0];
    const double x1 = inT[i * 68 + k0 + 1];
    const double x2 = inT[i * 68 + k0 + 2];
    const double x3 = inT[i * 68 + k0 + 3];
    const float4 wf = *(const float4*)&WT[i * 64 + j0];
    const double w0 = (double)wf.x, w1 = (double)wf.y;
    const double w2 = (double)wf.z, w3 = (double)wf.w;
    acc[0]  = fma(w0, x0, acc[0]);
    acc[1]  = fma(w0, x1, acc[1]);
    acc[2]  = fma(w0, x2, acc[2]);
    acc[3]  = fma(w0, x3, acc[3]);
    acc[4]  = fma(w1, x0, acc[4]);
    acc[5]  = fma(w1, x1, acc[5]);
    acc[6]  = fma(w1, x2, acc[6]);
    acc[7]  = fma(w1, x3, acc[7]);
    acc[8]  = fma(w2, x0, acc[8]);
    acc[9]  = fma(w2, x1, acc[9]);
    acc[10] = fma(w2, x2, acc[10]);
    acc[11] = fma(w2, x3, acc[11]);
    acc[12] = fma(w3, x0, acc[12]);
    acc[13] = fma(w3, x1, acc[13]);
    acc[14] = fma(w3, x2, acc[14]);
    acc[15] = fma(w3, x3, acc[15]);
  }
#pragma unroll
  for (int jj = 0; jj < 4; ++jj) {
#pragma unroll
    for (int kk = 0; kk < 4; ++kk) {
      const double a = acc[jj * 4 + kk];
      outT[(j0 + jj) * 68 + k0 + kk] = a > 0.0 ? a : 0.0;  // same relu as ref
    }
  }
}

__device__ __forceinline__ void heads20_f64(const double* __restrict__ actT,
                                            const float* __restrict__ whT,
                                            const float* __restrict__ by,
                                            const float* __restrict__ bh,
                                            const float* __restrict__ bd,
                                            double* __restrict__ headP, int t) {
  const int k = t & 63, w = t >> 6;
  double acc[5];
#pragma unroll
  for (int q = 0; q < 5; ++q) {
    const int r = w + 4 * q;
    acc[q] = (r < 6) ? (double)by[r]
           : (r < 12) ? (double)bh[r - 6]
           : (r < 18) ? (double)bd[r - 12] : 0.0;
  }
#pragma unroll 8
  for (int i = 0; i < 64; ++i) {
    const double x = actT[i * 68 + k];
#pragma unroll
    for (int q = 0; q < 5; ++q)
      acc[q] = fma(x, (double)whT[(w + 4 * q) * 64 + i], acc[q]);
  }
#pragma unroll
  for (int q = 0; q < 5; ++q) {
    const int r = w + 4 * q;
    if (r < 18) headP[k * 20 + r] = acc[q];
  }
}

// ---------------------------------------------------------------- kfix
// 256-thread block handles 8 m's; per flagged m runs the f64 LDS-gemm MLP.
__global__ __launch_bounds__(256, 1) void kfix(
    const float* __restrict__ v, const float* __restrict__ Hm,
    const float* __restrict__ y, const float* __restrict__ snr,
    const float* __restrict__ w1, const float* __restrict__ b1,
    const float* __restrict__ w2, const float* __restrict__ b2,
    const float* __restrict__ w3, const float* __restrict__ b3,
    const float* __restrict__ wy, const float* __restrict__ by,
    const float* __restrict__ wh, const float* __restrict__ bh,
    const float* __restrict__ wd, const float* __restrict__ bd,
    const double* __restrict__ hp_mean, const uint32_t* __restrict__ keys,
    float* __restrict__ out) {
  const int t = threadIdx.x;
  const int lane = t & 63;
  const int wvx = t >> 6;
  const int m0 = blockIdx.x * 8;
  const uint8_t* flags = (const uint8_t*)(out + O_vq);

  __shared__ uint32_t mfs[8];
  __shared__ __align__(32) char smem[120064];
  float*  w1T     = (float*)smem;                 // 576 f  [i<9][j]
  float*  w2T     = (float*)(smem + 2304);        // 4096 f [i][j]
  float*  w3T     = (float*)(smem + 18688);       // 4096 f [i][j]
  float*  whT     = (float*)(smem + 35072);       // 1280 f [r<20][i]
  double* actA64  = (double*)(smem + 40192);      // 64x68 d [row][k]
  double* actB64  = (double*)(smem + 75008);      // 64x68 d
  double* headP64 = (double*)(smem + 109824);     // 64x20 d [k][20]
  double* hp4     = actB64;                       // alias (pre-L1 only)

  if (t < 8) mfs[t] = flags[F_M + m0 + t];
  __syncthreads();
  bool any = false;
#pragma unroll
  for (int i = 0; i < 8; ++i) any |= (mfs[i] != 0);
  if (!any) return;

  // stage weights once (same transposed layouts as R5)
  for (int idx = t; idx < 576; idx += 256) {
    const int i = idx >> 6, j = idx & 63;
    w1T[idx] = w1[j * 9 + i];
  }
  for (int idx = t; idx < 4096; idx += 256) {
    const int i = idx >> 6, j = idx & 63;
    w2T[idx] = w2[j * 64 + i];
    w3T[idx] = w3[j * 64 + i];
  }
  for (int idx = t; idx < 1280; idx += 256) {
    const int r = idx >> 6, i = idx & 63;
    whT[idx] = (r < 6) ? wy[r * 64 + i]
             : (r < 12) ? wh[(r - 6) * 64 + i]
             : (r < 18) ? wd[(r - 12) * 64 + i] : 0.0f;
  }

#pragma unroll 1
  for (int mi = 0; mi < 8; ++mi) {
    const uint32_t mf = mfs[mi];
    if (mf == 0) continue;  // block-uniform
    const int m = m0 + mi;

    // hp partials, identical op order to k2
    {
      const float2* Hp = (const float2*)Hm + (size_t)m * 512;
      double acc = 0.0;
#pragma unroll
      for (int nn = 0; nn < 2; ++nn) {
        const float2 h2v = Hp[(2 * wvx + nn) * 64 + lane];
        acc = fma((double)h2v.x, (double)h2v.x, acc);
        acc = fma((double)h2v.y, (double)h2v.y, acc);
      }
      __syncthreads();  // weights staged / prior-m reads done before actB reuse
      hp4[wvx * 64 + lane] = acc;
    }
    __syncthreads();

    // wave 0: f64 features -> actA64 rows 0..8
    if (t < 64) {
      const double hp = ((hp4[lane] + hp4[64 + lane]) + hp4[128 + lane]) + hp4[192 + lane];
      const double tp = wave_sum_f64(hp);
      double ypart = 0.0;
      if (lane < 16) { const double yv = (double)y[m * 16 + lane]; ypart = yv * yv; }
      const double yp = wave_sum_f64(ypart);
      const float2 vv = ((const float2*)v)[m * 64 + lane];
      const float snrv = snr[m * 64 + lane];
      const double hpm = hp_mean[(m >> 8) * 64 + lane];
      double f[9];
      f[0] = (double)vv.x;
      f[1] = (double)vv.y;
      f[2] = (double)snrv;
      f[3] = hp;
      f[4] = hpm;
      f[5] = log1p(hp / ((tp - hp) + 1e-10));
      f[6] = log1p(tp);
      f[7] = log1p(yp);
      f[8] = sqrt(fma((double)vv.x, (double)vv.x,
                      fma((double)vv.y, (double)vv.y, 1e-10)));
#pragma unroll
      for (int i = 0; i < 9; ++i) actA64[i * 68 + lane] = f[i];
    }
    __syncthreads();

    gemm64_f64<9>(actA64, w1T, b1, actB64, t);
    __syncthreads();
    gemm64_f64<64>(actB64, w2T, b2, actA64, t);
    __syncthreads();
    gemm64_f64<64>(actA64, w3T, b3, actB64, t);
    __syncthreads();
    heads20_f64(actB64, whT, by, bh, bd, headP64, t);
    __syncthreads();

    // wave 0: refine flagged selections
    if (t < 64) {
      const int k = lane;
      const uint8_t f = flags[F_SAMPLE + (size_t)m * 64 + k];
      double lyd[6], lhd[6], ldd[6];
#pragma unroll
      for (int j = 0; j < 6; ++j) {
        lyd[j] = headP64[k * 20 + j];
        lhd[j] = headP64[k * 20 + 6 + j];
        ldd[j] = headP64[k * 20 + 12 + j];
      }
      const uint32_t g1k0 = keys[0], g1k1 = keys[1];
      const uint32_t g2k0 = keys[2], g2k1 = keys[3];
      const uint32_t g3k0 = keys[4], g3k1 = keys[5];
      const uint32_t eH = (uint32_t)(m * 64 + k) * 6u;

      float bHf, bDf;
      if (f & 1) {
        double s2[6];
#pragma unroll
        for (int j = 0; j < 6; ++j) {
          const float u = bits_to_unif(jax_randbits(g2k0, g2k1, eH + j, 6291456u));
          s2[j] = lhd[j] - log(-log((double)u));
        }
        int argH; double g; argmax_gap6(s2, argH, g);
        bHf = 16.0f * idx_to_bits(argH);
        out[O_Hbl + (size_t)m * 64 + k] = bHf;
#pragma unroll
        for (int j = 0; j < 6; ++j)
          out[O_wH + (size_t)(m * 64 + k) * 6 + j] = (j == argH) ? 1.0f : 0.0f;
      } else {
        bHf = out[O_Hbl + (size_t)m * 64 + k];
      }
      if (f & 2) {
        double s2[6];
#pragma unroll
        for (int j = 0; j < 6; ++j) {
          const float u = bits_to_unif(jax_randbits(g3k0, g3k1, eH + j, 6291456u));
          s2[j] = ldd[j] - log(-log((double)u));
        }
        int argD; double g; argmax_gap6(s2, argD, g);
        bDf = 2.0f * idx_to_bits(argD);
        out[O_dbl + (size_t)m * 64 + k] = bDf;
#pragma unroll
        for (int j = 0; j < 6; ++j)
          out[O_wd + (size_t)(m * 64 + k) * 6 + j] = (j == argD) ? 1.0f : 0.0f;
      } else {
        bDf = out[O_dbl + (size_t)m * 64 + k];
      }

      float bYf;
      if (mf & 2) {
        double lys2[6];
#pragma unroll
        for (int j = 0; j < 6; ++j) lys2[j] = wave_sum_f64(lyd[j]);
        int argY = 0;
        if (k == 0) {
          double s2[6];
#pragma unroll
          for (int j = 0; j < 6; ++j) {
            const float u = bits_to_unif(jax_randbits(g1k0, g1k1, (uint32_t)(m * 6 + j), 98304u));
            s2[j] = lys2[j] * (1.0 / 64.0) - log(-log((double)u));
          }
          double g; argmax_gap6(s2, argY, g);
        }
        argY = __shfl(argY, 0);
        bYf = 16.0f * idx_to_bits(argY);
        if (k == 0) {
          out[O_yba + m] = bYf;
#pragma unroll
          for (int j = 0; j < 6; ++j) out[O_wy + m * 6 + j] = (j == argY) ? 1.0f : 0.0f;
        }
      } else {
        bYf = out[O_yba + m];
      }

      out[O_eb + (size_t)m * 64 + k] = (bYf * 0.015625f + bHf) + bDf;
    }
    __syncthreads();  // headP64/actB64 safe before next mi reuses them
  }
}

// ---------------------------------------------------------------- LSQ quant
__device__ __forceinline__ int bits_to_idx(int bits) {
  return (bits <= 8) ? ((bits >> 1) - 1) : ((bits == 12) ? 4 : 5);
}

__device__ __forceinline__ float lsq1(float x, float ssv, float qn, float qp) {
  float t = x / ssv;
  t = fminf(fmaxf(t, qn), qp);
  return rintf(t) * ssv;
}

__global__ void k3_Hq(const float* __restrict__ Hm, const float* __restrict__ ss,
                      const float* __restrict__ Hbits, float* __restrict__ outHq) {
  const int id = blockIdx.x * blockDim.x + threadIdx.x;
  if (id >= 8388608) return;
  const int k = id & 63;
  const int m = id >> 9;
  const int bits = (int)Hbits[(size_t)m * 64 + k] >> 4;
  const int i = bits_to_idx(bits);
  const float ssv = ss[6 + i];
  const float qp = (float)((1 << (bits - 1)) - 1);
  const float qn = -(float)(1 << (bits - 1));
  const float2 x = ((const float2*)Hm)[id];
  float2 o;
  o.x = lsq1(x.x, ssv, qn, qp);
  o.y = lsq1(x.y, ssv, qn, qp);
  ((float2*)outHq)[id] = o;
}

__global__ void k4_vq(const float* __restrict__ v, const float* __restrict__ ss,
                      const float* __restrict__ dbits, float* __restrict__ outvq) {
  const int id = blockIdx.x * blockDim.x + threadIdx.x;
  if (id >= 1048576) return;
  const int bits = (int)dbits[id] >> 1;
  const int i = bits_to_idx(bits);
  const float ssv = ss[12 + i];
  const float qp = (float)((1 << (bits - 1)) - 1);
  const float qn = -(float)(1 << (bits - 1));
  const float2 x = ((const float2*)v)[id];
  float2 o;
  o.x = lsq1(x.x, ssv, qn, qp);
  o.y = lsq1(x.y, ssv, qn, qp);
  ((float2*)outvq)[id] = o;
}

__global__ void k5_yq(const float* __restrict__ y, const float* __restrict__ ss,
                      const float* __restrict__ ybits, float* __restrict__ outyq) {
  const int id = blockIdx.x * blockDim.x + threadIdx.x;
  if (id >= 131072) return;
  const int m = id >> 3;
  const int bits = (int)ybits[m] >> 4;
  const int i = bits_to_idx(bits);
  const float ssv = ss[i];
  const float qp = (float)((1 << (bits - 1)) - 1);
  const float qn = -(float)(1 << (bits - 1));
  const float2 x = ((const float2*)y)[id];
  float2 o;
  o.x = lsq1(x.x, ssv, qn, qp);
  o.y = lsq1(x.y, ssv, qn, qp);
  ((float2*)outyq)[id] = o;
}

// ---------------------------------------------------------------- launch
extern "C" void kernel_launch(void* const* d_in, const int* in_sizes, int n_in,
                              void* d_out, int out_size, void* d_ws, size_t ws_size,
                              hipStream_t stream) {
  const float* v   = (const float*)d_in[0];
  const float* Hm  = (const float*)d_in[1];
  const float* y   = (const float*)d_in[2];
  const float* snr = (const float*)d_in[3];
  const float* w1  = (const float*)d_in[4];
  const float* b1  = (const float*)d_in[5];
  const float* w2  = (const float*)d_in[6];
  const float* b2  = (const float*)d_in[7];
  const float* w3  = (const float*)d_in[8];
  const float* b3  = (const float*)d_in[9];
  const float* wy  = (const float*)d_in[10];
  const float* by  = (const float*)d_in[11];
  const float* wh  = (const float*)d_in[12];
  const float* bh  = (const float*)d_in[13];
  const float* wd  = (const float*)d_in[14];
  const float* bd  = (const float*)d_in[15];
  const float* sy  = (const float*)d_in[16];
  const float* sH  = (const float*)d_in[17];
  const float* sd  = (const float*)d_in[18];

  float* out = (float*)d_out;

  double* ws_partial = (double*)d_ws;
  double* ws_hpmean  = ws_partial + 32768;
  float*  ws_ss      = (float*)(ws_hpmean + 4096);
  uint32_t* ws_keys  = (uint32_t*)(ws_ss + 18);

  k0_setup<<<1, 64, 0, stream>>>(sy, sH, sd, ws_ss, ws_keys);
  k1a_hpower_partial<<<512, 128, 0, stream>>>(Hm, ws_partial);
  k1b_hpmean<<<16, 256, 0, stream>>>(ws_partial, ws_hpmean);
  k2_main<<<BL, 64, 0, stream>>>(v, Hm, y, snr, w1, b1, w2, b2, w3, b3,
                                 wy, by, wh, bh, wd, bd, ws_hpmean, ws_keys, out);
  kfix<<<BL / 8, 256, 0, stream>>>(v, Hm, y, snr, w1, b1, w2, b2, w3, b3,
                                   wy, by, wh, bh, wd, bd, ws_hpmean, ws_keys, out);
  k3_Hq<<<32768, 256, 0, stream>>>(Hm, ws_ss, out + O_Hbl, out + O_Hq);
  k4_vq<<<4096, 256, 0, stream>>>(v, ws_ss, out + O_dbl, out + O_vq);
  k5_yq<<<512, 256, 0, stream>>>(y, ws_ss, out + O_yba, out + O_yq);
}

// Round 9
// 820.197 us; speedup vs baseline: 3.2049x; 1.0037x over previous
//
#include <hip/hip_runtime.h>
#include <cstdint>

// ============================================================================
// TripleAdaptiveQuantizerV13 — round 14: 2-wave blocks for the R13 k2.
//
// R13 post-mortem: k2 516us (best), VGPR 84, no spill, conflicts 0, LDS 8KB,
// occ 33% (10.6 waves/CU vs 16-wave VGPR cap). VALUBusy 85% per-CU = ~38%
// per-SIMD issue: 62% of cycles all waves stalled on the scalar weight
// stream (40KB/m > 16KB sL1 -> L2-latency s_loads; 64B load = 32cyc work).
// Work-per-load is fixed (1 weight : 1 FMA) -> the lever is resident waves.
// 16384 one-wave WGs ride the ~16 WG-slot/CU limit; R14 packs 2 waves per
// 128-thread block (2 m/block, one per wave, per-wave 8KB LDS half, zero
// barriers, waves fully independent) -> half the WG slots at same VGPR/LDS
// caps, phase-locked weight streams share sL1. Body verbatim R13 per wave ->
// ly/lh/ld bit-identical -> flags / kfix / outputs unchanged.
// Tripwires: VGPR<=128 & WRITE~63MB (no spill); LDS_Block_Size 16384.
// ============================================================================

#define JAX_PARTITIONABLE 1

constexpr int BL = 64 * 256;  // 16384 (B*L)

// Output offsets (floats)
constexpr long long O_vq  = 0;
constexpr long long O_Hq  = 2097152;
constexpr long long O_yq  = 18874368;
constexpr long long O_eb  = 19136512;
constexpr long long O_wy  = 20185088;
constexpr long long O_wH  = 20283392;
constexpr long long O_wd  = 26574848;
constexpr long long O_yba = 32866304;
constexpr long long O_Hbl = 32882688;
constexpr long long O_dbl = 33931264;

// flag stash inside the v_q region (k4 overwrites all of v_q afterwards)
constexpr long long F_SAMPLE = 0;        // 1048576 bytes, 1 per (m,k)
constexpr long long F_M      = 1048576;  // 16384 bytes, 1 per m

#define MARGIN_THETA 3e-4

// ---------------------------------------------------------------- threefry
__device__ __forceinline__ uint32_t rotl32(uint32_t v, int d) {
  return (v << d) | (v >> (32 - d));
}

__device__ __forceinline__ void threefry2x32(uint32_t k0, uint32_t k1,
                                             uint32_t x0, uint32_t x1,
                                             uint32_t& o0, uint32_t& o1) {
  const uint32_t ks2 = k0 ^ k1 ^ 0x1BD11BDAu;
  x0 += k0; x1 += k1;
  x0 += x1; x1 = rotl32(x1, 13); x1 ^= x0;
  x0 += x1; x1 = rotl32(x1, 15); x1 ^= x0;
  x0 += x1; x1 = rotl32(x1, 26); x1 ^= x0;
  x0 += x1; x1 = rotl32(x1, 6);  x1 ^= x0;
  x0 += k1; x1 += ks2 + 1u;
  x0 += x1; x1 = rotl32(x1, 17); x1 ^= x0;
  x0 += x1; x1 = rotl32(x1, 29); x1 ^= x0;
  x0 += x1; x1 = rotl32(x1, 16); x1 ^= x0;
  x0 += x1; x1 = rotl32(x1, 24); x1 ^= x0;
  x0 += ks2; x1 += k0 + 2u;
  x0 += x1; x1 = rotl32(x1, 13); x1 ^= x0;
  x0 += x1; x1 = rotl32(x1, 15); x1 ^= x0;
  x0 += x1; x1 = rotl32(x1, 26); x1 ^= x0;
  x0 += x1; x1 = rotl32(x1, 6);  x1 ^= x0;
  x0 += k0; x1 += k1 + 3u;
  x0 += x1; x1 = rotl32(x1, 17); x1 ^= x0;
  x0 += x1; x1 = rotl32(x1, 29); x1 ^= x0;
  x0 += x1; x1 = rotl32(x1, 16); x1 ^= x0;
  x0 += x1; x1 = rotl32(x1, 24); x1 ^= x0;
  x0 += k1; x1 += ks2 + 4u;
  x0 += x1; x1 = rotl32(x1, 13); x1 ^= x0;
  x0 += x1; x1 = rotl32(x1, 15); x1 ^= x0;
  x0 += x1; x1 = rotl32(x1, 26); x1 ^= x0;
  x0 += x1; x1 = rotl32(x1, 6);  x1 ^= x0;
  x0 += ks2; x1 += k0 + 5u;
  o0 = x0; o1 = x1;
}

__device__ __forceinline__ uint32_t jax_randbits(uint32_t k0, uint32_t k1,
                                                 uint32_t e, uint32_t size) {
#if JAX_PARTITIONABLE
  (void)size;
  uint32_t o0, o1;
  threefry2x32(k0, k1, 0u, e, o0, o1);
  return o0 ^ o1;
#else
  const uint32_t half = size >> 1;
  uint32_t o0, o1;
  if (e < half) { threefry2x32(k0, k1, e, e + half, o0, o1); return o0; }
  threefry2x32(k0, k1, e - half, e, o0, o1); return o1;
#endif
}

// exact f32 replication of jax.random.uniform(minval=1e-10, maxval=1.0)
__device__ __forceinline__ float bits_to_unif(uint32_t bits) {
  float f = __uint_as_float((bits >> 9) | 0x3f800000u) - 1.0f;
  return fmaxf(1e-10f, f + 1e-10f);
}

// ---------------------------------------------------------------- helpers
__device__ __forceinline__ double wave_sum_f64(double x) {
#pragma unroll
  for (int off = 32; off > 0; off >>= 1) x += __shfl_xor(x, off);
  return x;
}

__device__ __forceinline__ void argmax_gap6(const double* s, int& arg, double& gap) {
  int a = 0;
#pragma unroll
  for (int j = 1; j < 6; ++j) if (s[j] > s[a]) a = j;
  double second = -1e300;
#pragma unroll
  for (int j = 0; j < 6; ++j) if (j != a && s[j] > second) second = s[j];
  arg = a; gap = s[a] - second;
}

__device__ __forceinline__ float idx_to_bits(int i) {
  return (float)((i < 4) ? 2 * (i + 1) : (i == 4 ? 12 : 16));
}

// ---------------------------------------------------------------- K0: ss + keys
__global__ void k0_setup(const float* __restrict__ sy, const float* __restrict__ sH,
                         const float* __restrict__ sd, float* __restrict__ ss,
                         uint32_t* __restrict__ keys) {
  const int t = threadIdx.x;
  if (t < 18) {
    const int tensor = t / 6, i = t % 6;
    const int qp_[6] = {1, 7, 31, 127, 2047, 32767};
    const long long sizes[3] = {262144LL, 16777216LL, 2097152LL};  // y, H, v
    const float* sarr = tensor == 0 ? sy : (tensor == 1 ? sH : sd);
    const double g64 = 1.0 / sqrt((double)(sizes[tensor] * (long long)qp_[i]));
    const float g32 = (float)g64;
    const float s = sarr[i];
    const float t1 = s * g32;
    ss[t] = t1 + (s - t1);  // _grad_scale forward, exact f32 sequence
  }
#if JAX_PARTITIONABLE
  if (t >= 32 && t < 35) {
    uint32_t o0, o1;
    threefry2x32(0u, 42u, 0u, (uint32_t)(t - 32), o0, o1);
    keys[(t - 32) * 2 + 0] = o0;
    keys[(t - 32) * 2 + 1] = o1;
  }
#else
  if (t == 32) {
    uint32_t a0, b0, a1, b1, a2, b2;
    threefry2x32(0u, 42u, 0u, 3u, a0, b0);
    threefry2x32(0u, 42u, 1u, 4u, a1, b1);
    threefry2x32(0u, 42u, 2u, 5u, a2, b2);
    keys[0] = a0; keys[1] = a1;
    keys[2] = a2; keys[3] = b0;
    keys[4] = b1; keys[5] = b2;
  }
#endif
}

// ---------------------------------------------------------------- K1: hp_mean
__global__ __launch_bounds__(128) void k1a_hpower_partial(
    const float* __restrict__ Hm, double* __restrict__ partial) {
  const int blk = blockIdx.x;       // 512 = 64 b * 8 l-chunks
  const int b = blk >> 3, lc = blk & 7;
  const int t = threadIdx.x;        // 128 = (k,c)
  const float* base = Hm + (size_t)(b * 256 + lc * 32) * 1024;
  double acc = 0.0;
  for (int l = 0; l < 32; ++l) {
#pragma unroll
    for (int n = 0; n < 8; ++n) {
      const float x = base[(size_t)l * 1024 + n * 128 + t];
      acc = fma((double)x, (double)x, acc);
    }
  }
  const double other = __shfl_xor(acc, 1);
  if ((t & 1) == 0) partial[(size_t)blk * 64 + (t >> 1)] = acc + other;
}

__global__ void k1b_hpmean(const double* __restrict__ partial,
                           double* __restrict__ hp_mean) {
  const int id = blockIdx.x * blockDim.x + threadIdx.x;  // 4096 = b*64+k
  if (id >= 4096) return;
  const int b = id >> 6, k = id & 63;
  double s = 0.0;
#pragma unroll
  for (int lc = 0; lc < 8; ++lc) s += partial[(size_t)(b * 8 + lc) * 64 + k];
  hp_mean[id] = s * (1.0 / 256.0);
}

// ---------------------------------------------------------------- layer 64->64
// 8KB-LDS two-pass layer, both passes rolled (R13's verified pattern):
//   pass1: j=0..31 -> buf; readback hout[0..31] EARLY (hin live, peak ~104);
//   pass2: j=32..63 -> same buf slots (DS in-order per wave: the readback
//   reads precede pass2's writes); readback hout[32..63] (hin dead).
// Chain per output: a = B[j]; fmaf(W[j*64+i], x, a) ascending i — identical
// numerics to R13; all values pass through f32 LDS exactly.
__device__ __forceinline__ void layer64_8k(const float (&hin)[64],
                                           const float* __restrict__ W,
                                           const float* __restrict__ B,
                                           float* __restrict__ buf, int lane,
                                           float (&hout)[64]) {
#pragma unroll 1
  for (int jg = 0; jg < 4; ++jg) {
    float a[8];
#pragma unroll
    for (int q = 0; q < 8; ++q) a[q] = B[jg * 8 + q];
#pragma unroll
    for (int i = 0; i < 64; ++i) {
      const float x = hin[i];
#pragma unroll
      for (int q = 0; q < 8; ++q)
        a[q] = fmaf(W[(jg * 8 + q) * 64 + i], x, a[q]);
    }
#pragma unroll
    for (int q = 0; q < 8; ++q)
      buf[(jg * 8 + q) * 64 + lane] = fmaxf(a[q], 0.0f);
  }
  // early readback of lower half (hin still live; same-wave DS ordering
  // guarantees these reads complete before pass2 overwrites the slots)
#pragma unroll
  for (int i = 0; i < 32; ++i) hout[i] = buf[i * 64 + lane];
#pragma unroll 1
  for (int jg = 0; jg < 4; ++jg) {
    float a[8];
#pragma unroll
    for (int q = 0; q < 8; ++q) a[q] = B[32 + jg * 8 + q];
#pragma unroll
    for (int i = 0; i < 64; ++i) {
      const float x = hin[i];
#pragma unroll
      for (int q = 0; q < 8; ++q)
        a[q] = fmaf(W[(32 + jg * 8 + q) * 64 + i], x, a[q]);
    }
#pragma unroll
    for (int q = 0; q < 8; ++q)
      buf[(jg * 8 + q) * 64 + lane] = fmaxf(a[q], 0.0f);
  }
#pragma unroll
  for (int i = 0; i < 32; ++i) hout[32 + i] = buf[i * 64 + lane];
}

// ---------------------------------------------------------------- K2: main
// TWO m per 128-thread block — one per wave, fully independent (no barriers).
// lane = k. Per-wave 8KB LDS half; weights via scalar pipe.
__global__ __launch_bounds__(128) void k2_main(
    const float* __restrict__ v, const float* __restrict__ Hm,
    const float* __restrict__ y, const float* __restrict__ snr,
    const float* __restrict__ w1, const float* __restrict__ b1,
    const float* __restrict__ w2, const float* __restrict__ b2,
    const float* __restrict__ w3, const float* __restrict__ b3,
    const float* __restrict__ wy, const float* __restrict__ by,
    const float* __restrict__ wh, const float* __restrict__ bh,
    const float* __restrict__ wd, const float* __restrict__ bd,
    const double* __restrict__ hp_mean, const uint32_t* __restrict__ keys,
    float* __restrict__ out) {
  const int t = threadIdx.x;
  const int lane = t & 63;
  const int wvx = t >> 6;
  const int m = blockIdx.x * 2 + wvx;

  __shared__ __align__(16) float smem[4096];  // 16384 B: two 8KB halves
  float* buf = smem + (wvx << 11);            // this wave's [j<32][lane]

  // ---- features (f64 op order identical to R13) ----
  float f[9];
  {
    const float2* Hp = (const float2*)Hm + (size_t)m * 512;
    double aw[4];
#pragma unroll
    for (int w = 0; w < 4; ++w) {
      double acc = 0.0;
#pragma unroll
      for (int nn = 0; nn < 2; ++nn) {
        const float2 h2v = Hp[(2 * w + nn) * 64 + lane];
        acc = fma((double)h2v.x, (double)h2v.x, acc);
        acc = fma((double)h2v.y, (double)h2v.y, acc);
      }
      aw[w] = acc;
    }
    const double hp = ((aw[0] + aw[1]) + aw[2]) + aw[3];
    const double tp = wave_sum_f64(hp);
    double ypart = 0.0;
    if (lane < 16) { const double yv = (double)y[m * 16 + lane]; ypart = yv * yv; }
    const double yp = wave_sum_f64(ypart);
    const float2 vv = ((const float2*)v)[m * 64 + lane];
    const float snrv = snr[m * 64 + lane];
    const double hpm = hp_mean[(m >> 8) * 64 + lane];
    f[0] = (float)vv.x;
    f[1] = (float)vv.y;
    f[2] = snrv;
    f[3] = (float)hp;
    f[4] = (float)hpm;
    f[5] = (float)log1p(hp / ((tp - hp) + 1e-10));
    f[6] = (float)log1p(tp);
    f[7] = (float)log1p(yp);
    f[8] = (float)sqrt(fma((double)vv.x, (double)vv.x,
                           fma((double)vv.y, (double)vv.y, 1e-10)));
  }

  // ---- L1: 9 -> 64, all static indices, registers only ----
  float h1[64];
#pragma unroll
  for (int j = 0; j < 64; ++j) {
    float a = b1[j];
#pragma unroll
    for (int i = 0; i < 9; ++i) a = fmaf(w1[j * 9 + i], f[i], a);
    h1[j] = fmaxf(a, 0.0f);
  }

  // ---- L2 / L3: 64 -> 64 via 8KB two-pass ----
  float h2[64];
  layer64_8k(h1, w2, b2, buf, lane, h2);
  float h3[64];
  layer64_8k(h2, w3, b3, buf, lane, h3);

  // ---- heads: 64 -> 6+6+6, registers (same chains as R13) ----
  float ly[6], lh[6], ld[6];
#pragma unroll
  for (int r = 0; r < 6; ++r) {
    float a = by[r];
#pragma unroll
    for (int i = 0; i < 64; ++i) a = fmaf(h3[i], wy[r * 64 + i], a);
    ly[r] = a;
  }
#pragma unroll
  for (int r = 0; r < 6; ++r) {
    float a = bh[r];
#pragma unroll
    for (int i = 0; i < 64; ++i) a = fmaf(h3[i], wh[r * 64 + i], a);
    lh[r] = a;
  }
#pragma unroll
  for (int r = 0; r < 6; ++r) {
    float a = bd[r];
#pragma unroll
    for (int i = 0; i < 64; ++i) a = fmaf(h3[i], wd[r * 64 + i], a);
    ld[r] = a;
  }

  // ---- phase C: selection (verbatim R13), lane = k ----
  const int k = lane;

  const uint32_t g1k0 = keys[0], g1k1 = keys[1];
  const uint32_t g2k0 = keys[2], g2k1 = keys[3];
  const uint32_t g3k0 = keys[4], g3k1 = keys[5];

  double sH[6], sD[6];
  const uint32_t eH = (uint32_t)(m * 64 + k) * 6u;
#pragma unroll
  for (int j = 0; j < 6; ++j) {
    const float u = bits_to_unif(jax_randbits(g2k0, g2k1, eH + j, 6291456u));
    sH[j] = (double)lh[j] + (double)(-logf(-logf(u)));
  }
#pragma unroll
  for (int j = 0; j < 6; ++j) {
    const float u = bits_to_unif(jax_randbits(g3k0, g3k1, eH + j, 6291456u));
    sD[j] = (double)ld[j] + (double)(-logf(-logf(u)));
  }
  int argH, argD; double gapH, gapD;
  argmax_gap6(sH, argH, gapH);
  argmax_gap6(sD, argD, gapD);

  double lysum[6];
#pragma unroll
  for (int j = 0; j < 6; ++j) lysum[j] = wave_sum_f64((double)ly[j]);

  int argY = 0; double gapY = 1e30;
  if (k == 0) {
    double sY[6];
#pragma unroll
    for (int j = 0; j < 6; ++j) {
      const float u = bits_to_unif(jax_randbits(g1k0, g1k1, (uint32_t)(m * 6 + j), 98304u));
      sY[j] = lysum[j] * (1.0 / 64.0) - log(-log((double)u));
    }
    argmax_gap6(sY, argY, gapY);
  }
  const int needY = __shfl((k == 0 && gapY < MARGIN_THETA) ? 1 : 0, 0);
  const bool fH = gapH < MARGIN_THETA;
  const bool fD = gapD < MARGIN_THETA;

  uint8_t* flags = (uint8_t*)(out + O_vq);
  flags[F_SAMPLE + (size_t)m * 64 + k] = (uint8_t)((fH ? 1 : 0) | (fD ? 2 : 0));
  const bool anyHD = __ballot(fH || fD) != 0ull;
  if (k == 0)
    flags[F_M + m] = (uint8_t)(((anyHD || needY) ? 1 : 0) | (needY ? 2 : 0));

  argY = __shfl(argY, 0);

  const float bY = 16.0f * idx_to_bits(argY);   // 2*N*bits
  const float bH = 16.0f * idx_to_bits(argH);
  const float bD = 2.0f * idx_to_bits(argD);

  if (k == 0) {
    out[O_yba + m] = bY;
#pragma unroll
    for (int j = 0; j < 6; ++j) out[O_wy + m * 6 + j] = (j == argY) ? 1.0f : 0.0f;
  }
  out[O_Hbl + (size_t)m * 64 + k] = bH;
  out[O_dbl + (size_t)m * 64 + k] = bD;
  out[O_eb + (size_t)m * 64 + k] = (bY * 0.015625f + bH) + bD;
#pragma unroll
  for (int j = 0; j < 6; ++j) {
    out[O_wH + (size_t)(m * 64 + k) * 6 + j] = (j == argH) ? 1.0f : 0.0f;
    out[O_wd + (size_t)(m * 64 + k) * 6 + j] = (j == argD) ? 1.0f : 0.0f;
  }
}

// ---------------------------------------------------------------- f64 helpers
// f64 variant for kfix: weights f32 in LDS (exact convert), act f64 [i][k].
template <int NI>
__device__ __forceinline__ void gemm64_f64(const double* __restrict__ inT,
                                           const float* __restrict__ WT,
                                           const float* __restrict__ bias,
                                           double* __restrict__ outT, int t) {
  const int k0 = (t & 15) * 4;
  const int j0 = (t >> 4) * 4;
  double acc[16];
#pragma unroll
  for (int jj = 0; jj < 4; ++jj) {
    const double bj = (double)bias[j0 + jj];
#pragma unroll
    for (int kk = 0; kk < 4; ++kk) acc[jj * 4 + kk] = bj;
  }
#pragma unroll 8
  for (int i = 0; i < NI; ++i) {
    const double x0 = inT[i * 68 + k0 + 0];
    const double x1 = inT[i * 68 + k0 + 1];
    const double x2 = inT[i * 68 + k0 + 2];
    const double x3 = inT[i * 68 + k0 + 3];
    const float4 wf = *(const float4*)&WT[i * 64 + j0];
    const double w0 = (double)wf.x, w1 = (double)wf.y;
    const double w2 = (double)wf.z, w3 = (double)wf.w;
    acc[0]  = fma(w0, x0, acc[0]);
    acc[1]  = fma(w0, x1, acc[1]);
    acc[2]  = fma(w0, x2, acc[2]);
    acc[3]  = fma(w0, x3, acc[3]);
    acc[4]  = fma(w1, x0, acc[4]);
    acc[5]  = fma(w1, x1, acc[5]);
    acc[6]  = fma(w1, x2, acc[6]);
    acc[7]  = fma(w1, x3, acc[7]);
    acc[8]  = fma(w2, x0, acc[8]);
    acc[9]  = fma(w2, x1, acc[9]);
    acc[10] = fma(w2, x2, acc[10]);
    acc[11] = fma(w2, x3, acc[11]);
    acc[12] = fma(w3, x0, acc[12]);
    acc[13] = fma(w3, x1, acc[13]);
    acc[14] = fma(w3, x2, acc[14]);
    acc[15] = fma(w3, x3, acc[15]);
  }
#pragma unroll
  for (int jj = 0; jj < 4; ++jj) {
#pragma unroll
    for (int kk = 0; kk < 4; ++kk) {
      const double a = acc[jj * 4 + kk];
      outT[(j0 + jj) * 68 + k0 + kk] = a > 0.0 ? a : 0.0;  // same relu as ref
    }
  }
}

__device__ __forceinline__ void heads20_f64(const double* __restrict__ actT,
                                            const float* __restrict__ whT,
                                            const float* __restrict__ by,
                                            const float* __restrict__ bh,
                                            const float* __restrict__ bd,
                                            double* __restrict__ headP, int t) {
  const int k = t & 63, w = t >> 6;
  double acc[5];
#pragma unroll
  for (int q = 0; q < 5; ++q) {
    const int r = w + 4 * q;
    acc[q] = (r < 6) ? (double)by[r]
           : (r < 12) ? (double)bh[r - 6]
           : (r < 18) ? (double)bd[r - 12] : 0.0;
  }
#pragma unroll 8
  for (int i = 0; i < 64; ++i) {
    const double x = actT[i * 68 + k];
#pragma unroll
    for (int q = 0; q < 5; ++q)
      acc[q] = fma(x, (double)whT[(w + 4 * q) * 64 + i], acc[q]);
  }
#pragma unroll
  for (int q = 0; q < 5; ++q) {
    const int r = w + 4 * q;
    if (r < 18) headP[k * 20 + r] = acc[q];
  }
}

// ---------------------------------------------------------------- kfix
// 256-thread block handles 8 m's; per flagged m runs the f64 LDS-gemm MLP.
__global__ __launch_bounds__(256, 1) void kfix(
    const float* __restrict__ v, const float* __restrict__ Hm,
    const float* __restrict__ y, const float* __restrict__ snr,
    const float* __restrict__ w1, const float* __restrict__ b1,
    const float* __restrict__ w2, const float* __restrict__ b2,
    const float* __restrict__ w3, const float* __restrict__ b3,
    const float* __restrict__ wy, const float* __restrict__ by,
    const float* __restrict__ wh, const float* __restrict__ bh,
    const float* __restrict__ wd, const float* __restrict__ bd,
    const double* __restrict__ hp_mean, const uint32_t* __restrict__ keys,
    float* __restrict__ out) {
  const int t = threadIdx.x;
  const int lane = t & 63;
  const int wvx = t >> 6;
  const int m0 = blockIdx.x * 8;
  const uint8_t* flags = (const uint8_t*)(out + O_vq);

  __shared__ uint32_t mfs[8];
  __shared__ __align__(32) char smem[120064];
  float*  w1T     = (float*)smem;                 // 576 f  [i<9][j]
  float*  w2T     = (float*)(smem + 2304);        // 4096 f [i][j]
  float*  w3T     = (float*)(smem + 18688);       // 4096 f [i][j]
  float*  whT     = (float*)(smem + 35072);       // 1280 f [r<20][i]
  double* actA64  = (double*)(smem + 40192);      // 64x68 d [row][k]
  double* actB64  = (double*)(smem + 75008);      // 64x68 d
  double* headP64 = (double*)(smem + 109824);     // 64x20 d [k][20]
  double* hp4     = actB64;                       // alias (pre-L1 only)

  if (t < 8) mfs[t] = flags[F_M + m0 + t];
  __syncthreads();
  bool any = false;
#pragma unroll
  for (int i = 0; i < 8; ++i) any |= (mfs[i] != 0);
  if (!any) return;

  // stage weights once (same transposed layouts as R5)
  for (int idx = t; idx < 576; idx += 256) {
    const int i = idx >> 6, j = idx & 63;
    w1T[idx] = w1[j * 9 + i];
  }
  for (int idx = t; idx < 4096; idx += 256) {
    const int i = idx >> 6, j = idx & 63;
    w2T[idx] = w2[j * 64 + i];
    w3T[idx] = w3[j * 64 + i];
  }
  for (int idx = t; idx < 1280; idx += 256) {
    const int r = idx >> 6, i = idx & 63;
    whT[idx] = (r < 6) ? wy[r * 64 + i]
             : (r < 12) ? wh[(r - 6) * 64 + i]
             : (r < 18) ? wd[(r - 12) * 64 + i] : 0.0f;
  }

#pragma unroll 1
  for (int mi = 0; mi < 8; ++mi) {
    const uint32_t mf = mfs[mi];
    if (mf == 0) continue;  // block-uniform
    const int m = m0 + mi;

    // hp partials, identical op order to k2
    {
      const float2* Hp = (const float2*)Hm + (size_t)m * 512;
      double acc = 0.0;
#pragma unroll
      for (int nn = 0; nn < 2; ++nn) {
        const float2 h2v = Hp[(2 * wvx + nn) * 64 + lane];
        acc = fma((double)h2v.x, (double)h2v.x, acc);
        acc = fma((double)h2v.y, (double)h2v.y, acc);
      }
      __syncthreads();  // weights staged / prior-m reads done before actB reuse
      hp4[wvx * 64 + lane] = acc;
    }
    __syncthreads();

    // wave 0: f64 features -> actA64 rows 0..8
    if (t < 64) {
      const double hp = ((hp4[lane] + hp4[64 + lane]) + hp4[128 + lane]) + hp4[192 + lane];
      const double tp = wave_sum_f64(hp);
      double ypart = 0.0;
      if (lane < 16) { const double yv = (double)y[m * 16 + lane]; ypart = yv * yv; }
      const double yp = wave_sum_f64(ypart);
      const float2 vv = ((const float2*)v)[m * 64 + lane];
      const float snrv = snr[m * 64 + lane];
      const double hpm = hp_mean[(m >> 8) * 64 + lane];
      double f[9];
      f[0] = (double)vv.x;
      f[1] = (double)vv.y;
      f[2] = (double)snrv;
      f[3] = hp;
      f[4] = hpm;
      f[5] = log1p(hp / ((tp - hp) + 1e-10));
      f[6] = log1p(tp);
      f[7] = log1p(yp);
      f[8] = sqrt(fma((double)vv.x, (double)vv.x,
                      fma((double)vv.y, (double)vv.y, 1e-10)));
#pragma unroll
      for (int i = 0; i < 9; ++i) actA64[i * 68 + lane] = f[i];
    }
    __syncthreads();

    gemm64_f64<9>(actA64, w1T, b1, actB64, t);
    __syncthreads();
    gemm64_f64<64>(actB64, w2T, b2, actA64, t);
    __syncthreads();
    gemm64_f64<64>(actA64, w3T, b3, actB64, t);
    __syncthreads();
    heads20_f64(actB64, whT, by, bh, bd, headP64, t);
    __syncthreads();

    // wave 0: refine flagged selections
    if (t < 64) {
      const int k = lane;
      const uint8_t f = flags[F_SAMPLE + (size_t)m * 64 + k];
      double lyd[6], lhd[6], ldd[6];
#pragma unroll
      for (int j = 0; j < 6; ++j) {
        lyd[j] = headP64[k * 20 + j];
        lhd[j] = headP64[k * 20 + 6 + j];
        ldd[j] = headP64[k * 20 + 12 + j];
      }
      const uint32_t g1k0 = keys[0], g1k1 = keys[1];
      const uint32_t g2k0 = keys[2], g2k1 = keys[3];
      const uint32_t g3k0 = keys[4], g3k1 = keys[5];
      const uint32_t eH = (uint32_t)(m * 64 + k) * 6u;

      float bHf, bDf;
      if (f & 1) {
        double s2[6];
#pragma unroll
        for (int j = 0; j < 6; ++j) {
          const float u = bits_to_unif(jax_randbits(g2k0, g2k1, eH + j, 6291456u));
          s2[j] = lhd[j] - log(-log((double)u));
        }
        int argH; double g; argmax_gap6(s2, argH, g);
        bHf = 16.0f * idx_to_bits(argH);
        out[O_Hbl + (size_t)m * 64 + k] = bHf;
#pragma unroll
        for (int j = 0; j < 6; ++j)
          out[O_wH + (size_t)(m * 64 + k) * 6 + j] = (j == argH) ? 1.0f : 0.0f;
      } else {
        bHf = out[O_Hbl + (size_t)m * 64 + k];
      }
      if (f & 2) {
        double s2[6];
#pragma unroll
        for (int j = 0; j < 6; ++j) {
          const float u = bits_to_unif(jax_randbits(g3k0, g3k1, eH + j, 6291456u));
          s2[j] = ldd[j] - log(-log((double)u));
        }
        int argD; double g; argmax_gap6(s2, argD, g);
        bDf = 2.0f * idx_to_bits(argD);
        out[O_dbl + (size_t)m * 64 + k] = bDf;
#pragma unroll
        for (int j = 0; j < 6; ++j)
          out[O_wd + (size_t)(m * 64 + k) * 6 + j] = (j == argD) ? 1.0f : 0.0f;
      } else {
        bDf = out[O_dbl + (size_t)m * 64 + k];
      }

      float bYf;
      if (mf & 2) {
        double lys2[6];
#pragma unroll
        for (int j = 0; j < 6; ++j) lys2[j] = wave_sum_f64(lyd[j]);
        int argY = 0;
        if (k == 0) {
          double s2[6];
#pragma unroll
          for (int j = 0; j < 6; ++j) {
            const float u = bits_to_unif(jax_randbits(g1k0, g1k1, (uint32_t)(m * 6 + j), 98304u));
            s2[j] = lys2[j] * (1.0 / 64.0) - log(-log((double)u));
          }
          double g; argmax_gap6(s2, argY, g);
        }
        argY = __shfl(argY, 0);
        bYf = 16.0f * idx_to_bits(argY);
        if (k == 0) {
          out[O_yba + m] = bYf;
#pragma unroll
          for (int j = 0; j < 6; ++j) out[O_wy + m * 6 + j] = (j == argY) ? 1.0f : 0.0f;
        }
      } else {
        bYf = out[O_yba + m];
      }

      out[O_eb + (size_t)m * 64 + k] = (bYf * 0.015625f + bHf) + bDf;
    }
    __syncthreads();  // headP64/actB64 safe before next mi reuses them
  }
}

// ---------------------------------------------------------------- LSQ quant
__device__ __forceinline__ int bits_to_idx(int bits) {
  return (bits <= 8) ? ((bits >> 1) - 1) : ((bits == 12) ? 4 : 5);
}

__device__ __forceinline__ float lsq1(float x, float ssv, float qn, float qp) {
  float t = x / ssv;
  t = fminf(fmaxf(t, qn), qp);
  return rintf(t) * ssv;
}

__global__ void k3_Hq(const float* __restrict__ Hm, const float* __restrict__ ss,
                      const float* __restrict__ Hbits, float* __restrict__ outHq) {
  const int id = blockIdx.x * blockDim.x + threadIdx.x;
  if (id >= 8388608) return;
  const int k = id & 63;
  const int m = id >> 9;
  const int bits = (int)Hbits[(size_t)m * 64 + k] >> 4;
  const int i = bits_to_idx(bits);
  const float ssv = ss[6 + i];
  const float qp = (float)((1 << (bits - 1)) - 1);
  const float qn = -(float)(1 << (bits - 1));
  const float2 x = ((const float2*)Hm)[id];
  float2 o;
  o.x = lsq1(x.x, ssv, qn, qp);
  o.y = lsq1(x.y, ssv, qn, qp);
  ((float2*)outHq)[id] = o;
}

__global__ void k4_vq(const float* __restrict__ v, const float* __restrict__ ss,
                      const float* __restrict__ dbits, float* __restrict__ outvq) {
  const int id = blockIdx.x * blockDim.x + threadIdx.x;
  if (id >= 1048576) return;
  const int bits = (int)dbits[id] >> 1;
  const int i = bits_to_idx(bits);
  const float ssv = ss[12 + i];
  const float qp = (float)((1 << (bits - 1)) - 1);
  const float qn = -(float)(1 << (bits - 1));
  const float2 x = ((const float2*)v)[id];
  float2 o;
  o.x = lsq1(x.x, ssv, qn, qp);
  o.y = lsq1(x.y, ssv, qn, qp);
  ((float2*)outvq)[id] = o;
}

__global__ void k5_yq(const float* __restrict__ y, const float* __restrict__ ss,
                      const float* __restrict__ ybits, float* __restrict__ outyq) {
  const int id = blockIdx.x * blockDim.x + threadIdx.x;
  if (id >= 131072) return;
  const int m = id >> 3;
  const int bits = (int)ybits[m] >> 4;
  const int i = bits_to_idx(bits);
  const float ssv = ss[i];
  const float qp = (float)((1 << (bits - 1)) - 1);
  const float qn = -(float)(1 << (bits - 1));
  const float2 x = ((const float2*)y)[id];
  float2 o;
  o.x = lsq1(x.x, ssv, qn, qp);
  o.y = lsq1(x.y, ssv, qn, qp);
  ((float2*)outyq)[id] = o;
}

// ---------------------------------------------------------------- launch
extern "C" void kernel_launch(void* const* d_in, const int* in_sizes, int n_in,
                              void* d_out, int out_size, void* d_ws, size_t ws_size,
                              hipStream_t stream) {
  const float* v   = (const float*)d_in[0];
  const float* Hm  = (const float*)d_in[1];
  const float* y   = (const float*)d_in[2];
  const float* snr = (const float*)d_in[3];
  const float* w1  = (const float*)d_in[4];
  const float* b1  = (const float*)d_in[5];
  const float* w2  = (const float*)d_in[6];
  const float* b2  = (const float*)d_in[7];
  const float* w3  = (const float*)d_in[8];
  const float* b3  = (const float*)d_in[9];
  const float* wy  = (const float*)d_in[10];
  const float* by  = (const float*)d_in[11];
  const float* wh  = (const float*)d_in[12];
  const float* bh  = (const float*)d_in[13];
  const float* wd  = (const float*)d_in[14];
  const float* bd  = (const float*)d_in[15];
  const float* sy  = (const float*)d_in[16];
  const float* sH  = (const float*)d_in[17];
  const float* sd  = (const float*)d_in[18];

  float* out = (float*)d_out;

  double* ws_partial = (double*)d_ws;
  double* ws_hpmean  = ws_partial + 32768;
  float*  ws_ss      = (float*)(ws_hpmean + 4096);
  uint32_t* ws_keys  = (uint32_t*)(ws_ss + 18);

  k0_setup<<<1, 64, 0, stream>>>(sy, sH, sd, ws_ss, ws_keys);
  k1a_hpower_partial<<<512, 128, 0, stream>>>(Hm, ws_partial);
  k1b_hpmean<<<16, 256, 0, stream>>>(ws_partial, ws_hpmean);
  k2_main<<<BL / 2, 128, 0, stream>>>(v, Hm, y, snr, w1, b1, w2, b2, w3, b3,
                                      wy, by, wh, bh, wd, bd, ws_hpmean, ws_keys, out);
  kfix<<<BL / 8, 256, 0, stream>>>(v, Hm, y, snr, w1, b1, w2, b2, w3, b3,
                                   wy, by, wh, bh, wd, bd, ws_hpmean, ws_keys, out);
  k3_Hq<<<32768, 256, 0, stream>>>(Hm, ws_ss, out + O_Hbl, out + O_Hq);
  k4_vq<<<4096, 256, 0, stream>>>(v, ws_ss, out + O_dbl, out + O_vq);
  k5_yq<<<512, 256, 0, stream>>>(y, ws_ss, out + O_yba, out + O_yq);
}